// Round 14
// baseline (1243.855 us; speedup 1.0000x reference)
//
#include <hip/hip_runtime.h>

typedef __bf16 bf16_t;
typedef __bf16 bf16x8 __attribute__((ext_vector_type(8)));
typedef float f32x4 __attribute__((ext_vector_type(4)));
typedef float f32x16 __attribute__((ext_vector_type(16)));
typedef unsigned short u16;

#define DEV static __device__ __forceinline__

DEV float bf2f(u16 u) { __bf16 h = __builtin_bit_cast(__bf16, u); return (float)h; }
DEV u16 f2bf(float f) { __bf16 h = (__bf16)f; return __builtin_bit_cast(u16, h); }

// async global->LDS, 16B per lane; lds base must be wave-uniform.
DEV void gll16(bf16_t* lds, const bf16_t* g) {
    __builtin_amdgcn_global_load_lds(
        (const __attribute__((address_space(1))) void*)g,
        (__attribute__((address_space(3))) void*)lds, 16, 0, 0);
}

#define WAITV(N) asm volatile("s_waitcnt vmcnt(" #N ")" ::: "memory")

// ---------------------------------------------------------------------------
// 256x256-tile GEMM, 8 waves (2M x 4N), BK=64, 128KiB dbuf LDS, 32x32x16 MFMA.
// m201-style 8-phase schedule (2 K-tiles/iter), counted vmcnt(6) at phases 4/8
// (3 half-tiles in flight, never 0 mid-loop). Stage slots verified hazard-free:
//  ph1:A1(t1)  ph3:B0+B1(t2)  ph4:A0(t2)  ph5:A1(t2)  ph6:B0(t3)  ph7:B1(t3)
//  ph8:A0(t3); B-halves free after their ni1-phase, A-halves after mi23-phase.
// EPI: 0 = bf16 out (+f32 bias if non-null), 1 = bf16 out + bias + relu
// ---------------------------------------------------------------------------
template <int EPI>
__global__ __launch_bounds__(512, 1)
void gemm8p(const bf16_t* __restrict__ A, int lda,
            const bf16_t* __restrict__ Bt, int ldb,
            bf16_t* __restrict__ C, int ldc,
            const float* __restrict__ bias, int K,
            long kadv, long cadv)
{
    __shared__ bf16_t Asm[2 * 2 * 8192];   // [buf][half][128*64]
    __shared__ bf16_t Bsm[2 * 2 * 8192];
    const int tid = threadIdx.x, w = tid >> 6, l = tid & 63;
    const int z = blockIdx.z;
    A  += (size_t)z * kadv;
    Bt += (size_t)z * kadv;
    C  += (size_t)z * cadv;

    const int gx = gridDim.x;
    int lin = blockIdx.y * gx + blockIdx.x;
    const int nlin = gx * gridDim.y;
    lin = (lin & 7) * (nlin >> 3) + (lin >> 3);
    const size_t row0 = (size_t)(lin / gx) * 256;
    const size_t col0 = (size_t)(lin % gx) * 256;

    const int wr = w >> 2, wc = w & 3;
    const int bh = wc >> 1;
    const int browoff = (wc & 1) * 64;
    const int r32 = l & 31, hk = l >> 5, sw = l & 7;

    const int srow = w * 8 + (l >> 3);
    const int sslot8 = ((l & 7) ^ ((l >> 3) & 7)) * 8;
    const bf16_t* AgH0 = A  + (row0 + srow) * (size_t)lda + sslot8;
    const bf16_t* BgH0 = Bt + (col0 + srow) * (size_t)ldb + sslot8;
    const size_t a128 = (size_t)128 * lda, b128 = (size_t)128 * ldb;
    const size_t a64  = (size_t)64 * lda,  b64  = (size_t)64 * ldb;
    const int wlds = w * 512;

// half-tile stage: p = 0:A-half0 1:A-half1 2:B-half0 3:B-half1 (2 loads each)
#define STAGE_PAIR(buf, tt, p)                                                 \
    do {                                                                       \
        const int koff = (tt) * 64;                                            \
        if ((p) == 0) {                                                        \
            gll16(Asm + ((buf)*2+0)*8192 + wlds,        AgH0 + koff);          \
            gll16(Asm + ((buf)*2+0)*8192 + 4096 + wlds, AgH0 + koff + a64);    \
        } else if ((p) == 1) {                                                 \
            gll16(Asm + ((buf)*2+1)*8192 + wlds,        AgH0 + a128 + koff);   \
            gll16(Asm + ((buf)*2+1)*8192 + 4096 + wlds, AgH0 + a128 + koff + a64); \
        } else if ((p) == 2) {                                                 \
            gll16(Bsm + ((buf)*2+0)*8192 + wlds,        BgH0 + koff);          \
            gll16(Bsm + ((buf)*2+0)*8192 + 4096 + wlds, BgH0 + koff + b64);    \
        } else {                                                               \
            gll16(Bsm + ((buf)*2+1)*8192 + wlds,        BgH0 + b128 + koff);   \
            gll16(Bsm + ((buf)*2+1)*8192 + 4096 + wlds, BgH0 + b128 + koff + b64); \
        }                                                                      \
    } while (0)

#define RD_A(base, half)                                                       \
    _Pragma("unroll")                                                          \
    for (int j = 0; j < 2; j++)                                                \
        _Pragma("unroll")                                                      \
        for (int ks = 0; ks < 4; ks++)                                         \
            aF[j][ks] = *(const bf16x8*)&(base)[(((half)*2+j)*32 + r32)*64 + ((ks*2+hk)^sw)*8]

#define RD_B(base, ni, dst)                                                    \
    _Pragma("unroll")                                                          \
    for (int ks = 0; ks < 4; ks++)                                             \
        dst[ks] = *(const bf16x8*)&(base)[(browoff + (ni)*32 + r32)*64 + ((ks*2+hk)^sw)*8]

#define MM(mb, ni, bsrc)                                                       \
    _Pragma("unroll")                                                          \
    for (int j = 0; j < 2; j++)                                                \
        _Pragma("unroll")                                                      \
        for (int ks = 0; ks < 4; ks++)                                         \
            acc[(mb)+j][ni] = __builtin_amdgcn_mfma_f32_32x32x16_bf16(aF[j][ks], bsrc[ks], acc[(mb)+j][ni], 0, 0, 0)

#define BAR __builtin_amdgcn_s_barrier()
#define PRIO1 __builtin_amdgcn_s_setprio(1)
#define PRIO0 __builtin_amdgcn_s_setprio(0)

    f32x16 acc[4][2] = {};
    const int NT = K >> 6;      // even (K = 1024 -> 16)

    // prologue: tile0 fully + tile1 {B0,B1,A0}; drain all but tile1's 3 halves
    STAGE_PAIR(0, 0, 2); STAGE_PAIR(0, 0, 3); STAGE_PAIR(0, 0, 0); STAGE_PAIR(0, 0, 1);
    STAGE_PAIR(1, 1, 2); STAGE_PAIR(1, 1, 3); STAGE_PAIR(1, 1, 0);
    WAITV(6);
    __builtin_amdgcn_sched_barrier(0);
    BAR;

    const bf16_t* A0b = Asm + (0 + wr) * 8192;   // buf0
    const bf16_t* B0b = Bsm + (0 + bh) * 8192;
    const bf16_t* A1b = Asm + (2 + wr) * 8192;   // buf1
    const bf16_t* B1b = Bsm + (2 + bh) * 8192;

    bf16x8 aF[2][4], bF0[4], bF1[4];

    for (int it = 0; it < (NT >> 1); ++it) {
        const int t1 = 2 * it + 1, t2 = 2 * it + 2, t3 = 2 * it + 3;
        const bool h2 = (t2 < NT);

        // ---- K-tile 2it (buf0) ----
        // ph1: A(mi01)+B(ni0); stage A1(t1)
        RD_A(A0b, 0); RD_B(B0b, 0, bF0);
        STAGE_PAIR(1, t1, 1);
        BAR; PRIO1; MM(0, 0, bF0); PRIO0; BAR;
        // ph2: B(ni1)
        RD_B(B0b, 1, bF1);
        BAR; PRIO1; MM(0, 1, bF1); PRIO0; BAR;
        // ph3: A(mi23); stage B0,B1(t2)
        RD_A(A0b, 1);
        if (h2) { STAGE_PAIR(0, t2, 2); STAGE_PAIR(0, t2, 3); }
        BAR; PRIO1; MM(2, 1, bF1); PRIO0; BAR;
        // ph4: reg-only; stage A0(t2); counted wait
        if (h2) STAGE_PAIR(0, t2, 0);
        BAR; PRIO1; MM(2, 0, bF0); PRIO0;
        if (h2) { WAITV(6); } else { WAITV(0); }
        __builtin_amdgcn_sched_barrier(0);
        BAR;

        // ---- K-tile 2it+1 (buf1) ----
        // ph5: A(mi01)+B(ni0); stage A1(t2)
        RD_A(A1b, 0); RD_B(B1b, 0, bF0);
        if (h2) STAGE_PAIR(0, t2, 1);
        BAR; PRIO1; MM(0, 0, bF0); PRIO0; BAR;
        // ph6: B(ni1); stage B0(t3)
        RD_B(B1b, 1, bF1);
        if (h2) STAGE_PAIR(1, t3, 2);
        BAR; PRIO1; MM(0, 1, bF1); PRIO0; BAR;
        // ph7: A(mi23); stage B1(t3)
        RD_A(A1b, 1);
        if (h2) STAGE_PAIR(1, t3, 3);
        BAR; PRIO1; MM(2, 1, bF1); PRIO0; BAR;
        // ph8: reg-only; stage A0(t3); counted wait
        if (h2) STAGE_PAIR(1, t3, 0);
        BAR; PRIO1; MM(2, 0, bF0); PRIO0;
        if (h2) { WAITV(6); } else { WAITV(0); }
        __builtin_amdgcn_sched_barrier(0);
        BAR;
    }
#undef STAGE_PAIR
#undef RD_A
#undef RD_B
#undef MM

#pragma unroll
    for (int ni = 0; ni < 2; ni++) {
        size_t c = col0 + wc * 64 + ni * 32 + r32;
        float bv = bias ? bias[c] : 0.f;
#pragma unroll
        for (int mi = 0; mi < 4; mi++) {
            size_t rb = row0 + wr * 128 + mi * 32 + hk * 4;
#pragma unroll
            for (int reg = 0; reg < 16; reg++) {
                size_t r = rb + (reg & 3) + 8 * (reg >> 2);
                float v = acc[mi][ni][reg] + bv;
                if (EPI == 1) v = fmaxf(v, 0.f);
                C[r * ldc + c] = (bf16_t)v;
            }
        }
    }
}

// ---------------------------------------------------------------------------
// 128x128-tile GEMM, 4 waves, BK=64, dbuf LDS, 32x32x16 MFMA (round-11).
// EPI: 0 bf16+bias, 1 +relu, 2 f32*scale, 3 bf16*scale
// ---------------------------------------------------------------------------
template <int EPI>
__global__ __launch_bounds__(256)
void gemm_db(const bf16_t* __restrict__ A, int lda, long sA,
             const bf16_t* __restrict__ Bt, int ldb, long sB,
             void* __restrict__ Cv, int ldc, long sC,
             const float* __restrict__ bias, int K, float scale)
{
    __shared__ bf16_t Asm[2][128 * 64];
    __shared__ bf16_t Bsm[2][128 * 64];
    const int tid = threadIdx.x, w = tid >> 6, l = tid & 63;
    const int bz = blockIdx.z;

    const int gx = gridDim.x;
    int lin = blockIdx.y * gx + blockIdx.x;
    const int nlin = gx * gridDim.y;
    lin = (lin & 7) * (nlin >> 3) + (lin >> 3);
    const size_t row0 = (size_t)(lin / gx) * 128;
    const size_t col0 = (size_t)(lin % gx) * 128;

    A  += (size_t)bz * sA;
    Bt += (size_t)bz * sB;

    const int lr = l >> 3;
    const int sl = (l & 7) ^ lr;
    const bf16_t* Ag = A  + (row0 + (size_t)(w * 32) + lr) * lda + sl * 8;
    const bf16_t* Bg = Bt + (col0 + (size_t)(w * 32) + lr) * ldb + sl * 8;
    const int wlds = (w * 32) * 64;

#define STA(buf, tt)                                                           \
    do { const int ko = (tt) * 64;                                             \
        _Pragma("unroll")                                                      \
        for (int c = 0; c < 4; c++)                                            \
            gll16(&Asm[buf][wlds + c * 8 * 64], Ag + (size_t)(c * 8) * lda + ko); \
    } while (0)
#define STB(buf, tt)                                                           \
    do { const int ko = (tt) * 64;                                             \
        _Pragma("unroll")                                                      \
        for (int c = 0; c < 4; c++)                                            \
            gll16(&Bsm[buf][wlds + c * 8 * 64], Bg + (size_t)(c * 8) * ldb + ko); \
    } while (0)

    const int wm = (w >> 1) * 64, wn = (w & 1) * 64;
    const int r32 = l & 31, hk = l >> 5, sw = l & 7;
    f32x16 acc[2][2] = {};
    const int NT = K >> 6;

    STA(0, 0); STB(0, 0);
    if (NT > 1) { STA(1, 1); WAITV(4); } else { WAITV(0); }
    __builtin_amdgcn_sched_barrier(0);
    __builtin_amdgcn_s_barrier();

    for (int t = 0; t < NT; ++t) {
        const int cur = t & 1, nxt = cur ^ 1;
        const bool hasN1 = (t + 1 < NT), hasN2 = (t + 2 < NT);

        bf16x8 a0[2][2], b0[2][2];
#pragma unroll
        for (int i = 0; i < 2; i++)
#pragma unroll
            for (int ks = 0; ks < 2; ks++) {
                a0[i][ks] = *(const bf16x8*)&Asm[cur][(wm + i * 32 + r32) * 64 + ((ks * 2 + hk) ^ sw) * 8];
                b0[i][ks] = *(const bf16x8*)&Bsm[cur][(wn + i * 32 + r32) * 64 + ((ks * 2 + hk) ^ sw) * 8];
            }
        if (hasN1) STB(nxt, t + 1);
        __builtin_amdgcn_s_setprio(1);
#pragma unroll
        for (int mi = 0; mi < 2; mi++)
#pragma unroll
            for (int ni = 0; ni < 2; ni++)
#pragma unroll
                for (int ks = 0; ks < 2; ks++)
                    acc[mi][ni] = __builtin_amdgcn_mfma_f32_32x32x16_bf16(a0[mi][ks], b0[ni][ks], acc[mi][ni], 0, 0, 0);
        __builtin_amdgcn_s_setprio(0);

        bf16x8 a1[2][2], b1[2][2];
#pragma unroll
        for (int i = 0; i < 2; i++)
#pragma unroll
            for (int ks = 0; ks < 2; ks++) {
                a1[i][ks] = *(const bf16x8*)&Asm[cur][(wm + i * 32 + r32) * 64 + (((2 + ks) * 2 + hk) ^ sw) * 8];
                b1[i][ks] = *(const bf16x8*)&Bsm[cur][(wn + i * 32 + r32) * 64 + (((2 + ks) * 2 + hk) ^ sw) * 8];
            }
        __builtin_amdgcn_s_setprio(1);
#pragma unroll
        for (int mi = 0; mi < 2; mi++)
#pragma unroll
            for (int ni = 0; ni < 2; ni++)
#pragma unroll
                for (int ks = 0; ks < 2; ks++)
                    acc[mi][ni] = __builtin_amdgcn_mfma_f32_32x32x16_bf16(a1[mi][ks], b1[ni][ks], acc[mi][ni], 0, 0, 0);
        __builtin_amdgcn_s_setprio(0);

        __builtin_amdgcn_s_barrier();
        if (hasN2) STA(cur, t + 2);
        if (hasN1) {
            if (hasN2) { WAITV(4); } else { WAITV(0); }
            __builtin_amdgcn_sched_barrier(0);
        }
        __builtin_amdgcn_s_barrier();
    }
#undef STA
#undef STB

#pragma unroll
    for (int ni = 0; ni < 2; ni++) {
        size_t c = col0 + wn + ni * 32 + r32;
        float bv = (EPI == 0 || EPI == 1) ? (bias ? bias[c] : 0.f) : 0.f;
#pragma unroll
        for (int mi = 0; mi < 2; mi++) {
            size_t rb = row0 + wm + mi * 32 + hk * 4;
#pragma unroll
            for (int reg = 0; reg < 16; reg++) {
                size_t r = rb + (reg & 3) + 8 * (reg >> 2);
                float v = acc[mi][ni][reg];
                if (EPI == 2) {
                    ((float*)Cv + (size_t)bz * sC)[r * ldc + c] = v * scale;
                } else if (EPI == 3) {
                    ((bf16_t*)Cv + (size_t)bz * sC)[r * ldc + c] = (bf16_t)(v * scale);
                } else {
                    v += bv;
                    if (EPI == 1) v = fmaxf(v, 0.f);
                    ((bf16_t*)Cv + (size_t)bz * sC)[r * ldc + c] = (bf16_t)v;
                }
            }
        }
    }
}

// ---------------------------------------------------------------------------
// one-shot preprocessing (round-13 version).
// ---------------------------------------------------------------------------
__global__ __launch_bounds__(256)
void prep_kernel(const float* __restrict__ Wq, const float* __restrict__ Wk,
                 const float* __restrict__ Wv, const float* __restrict__ Wf1,
                 const float* __restrict__ Wf2,
                 const float* __restrict__ bq, const float* __restrict__ bk,
                 const float* __restrict__ bv,
                 const int* __restrict__ ids, const float* __restrict__ emb,
                 bf16_t* __restrict__ wqkvTA, bf16_t* __restrict__ wf1TA,
                 bf16_t* __restrict__ wf2TA, float* __restrict__ qbiasA,
                 bf16_t* __restrict__ xb)
{
    __shared__ bf16_t tls[4][64 * 64];   // 32 KB
    const size_t DD = 1024 * 1024;
    int id = blockIdx.x;
    if (id < 4224) {
        const float* src; bf16_t* dst; int ldin, ldout, bx, by;
        if (id < 1152) {
            int layer = id / 192, r = id % 192, which = r >> 6, t = r & 63;
            src = (which == 0 ? Wq : which == 1 ? Wk : Wv) + (size_t)layer * DD;
            dst = wqkvTA + (size_t)layer * 3 * DD + (size_t)which * DD;
            ldin = 1024; ldout = 1024; bx = (t & 15) * 64; by = (t >> 4) * 256;
        } else if (id < 2688) {
            int i = id - 1152, layer = i >> 8, t = i & 255;
            src = Wf1 + (size_t)layer * 4 * DD; dst = wf1TA + (size_t)layer * 4 * DD;
            ldin = 4096; ldout = 1024; bx = (t & 63) * 64; by = (t >> 6) * 256;
        } else {
            int i = id - 2688, layer = i >> 8, t = i & 255;
            src = Wf2 + (size_t)layer * 4 * DD; dst = wf2TA + (size_t)layer * 4 * DD;
            ldin = 1024; ldout = 4096; bx = (t & 15) * 64; by = (t >> 4) * 256;
        }
        const int tid = threadIdx.x;
        const int cg = tid & 15, ri = tid >> 4;
#pragma unroll
        for (int sub = 0; sub < 4; sub++) {
#pragma unroll
            for (int k = 0; k < 4; k++) {
                int r = ri + k * 16;
                float4 v = *(const float4*)&src[(size_t)(by + sub * 64 + r) * ldin + bx + cg * 4];
                ushort4 o = {f2bf(v.x), f2bf(v.y), f2bf(v.z), f2bf(v.w)};
                int g = (cg ^ ((r >> 2) & 15) ^ sub) & 15;
                *(ushort4*)&tls[sub][r * 64 + g * 4] = o;
            }
        }
        __syncthreads();
        const int c = tid & 31, sub = c >> 3, j = c & 7;
#pragma unroll
        for (int p = 0; p < 8; p++) {
            int i = p * 8 + (tid >> 5);
            u16 vals[8];
#pragma unroll
            for (int m = 0; m < 8; m++) {
                int rr = j * 8 + m;
                int gg = ((i >> 2) ^ (rr >> 2) ^ sub) & 15;
                vals[m] = __builtin_bit_cast(u16, tls[sub][rr * 64 + gg * 4 + (i & 3)]);
            }
            uint4 ov;
            ov.x = (unsigned)vals[0] | ((unsigned)vals[1] << 16);
            ov.y = (unsigned)vals[2] | ((unsigned)vals[3] << 16);
            ov.z = (unsigned)vals[4] | ((unsigned)vals[5] << 16);
            ov.w = (unsigned)vals[6] | ((unsigned)vals[7] << 16);
            *(uint4*)&dst[(size_t)(bx + i) * ldout + by + c * 8] = ov;
        }
        return;
    }
    id -= 4224;
    if (id < 72) {
        int i = id * 256 + threadIdx.x;
        int lyr = i / 3072, j = i - lyr * 3072;
        qbiasA[i] = (j < 1024) ? bq[lyr * 1024 + j]
                  : (j < 2048) ? bk[lyr * 1024 + j - 1024]
                               : bv[lyr * 1024 + j - 2048];
        return;
    }
    id -= 72;
    const int row = id;
    const int s = row & 1023;
    const int eid = ids[row];
    const float* er = emb + (size_t)eid * 1024;
    bf16_t* br = xb + (size_t)row * 1024;
#pragma unroll
    for (int k = 0; k < 2; k++) {
        int i = threadIdx.x + 256 * k;
        int d = 2 * i;
        float dv = expf((float)d * -0.008994473019508f);
        float ph = (float)s * dv;
        float sv, cv;
        sincosf(ph, &sv, &cv);
        float2 ev = *(const float2*)&er[d];
        ushort2 bo = {f2bf(ev.x + sv), f2bf(ev.y + cv)};
        *(ushort2*)&br[d] = bo;
    }
}

// ---------------------------------------------------------------------------
// merged masked-softmax over bf16 scores (blocks 0..1023) + V^T transpose
// (blocks 1024..2047).
// ---------------------------------------------------------------------------
__global__ __launch_bounds__(256)
void softvt_kernel(const bf16_t* __restrict__ sc, const int* __restrict__ amask,
                   bf16_t* __restrict__ p, const bf16_t* __restrict__ qkv,
                   bf16_t* __restrict__ vt)
{
    __shared__ bf16_t tls[64][72];
    int bid = blockIdx.x;
    if (bid < 1024) {
        const int row = bid * 4 + (threadIdx.x >> 6);
        const int l = threadIdx.x & 63;
        const int b = row >> 10;
        const bf16_t* s = sc + (size_t)row * 1024;
        const int* m = amask + (size_t)b * 1024;
        float v[16];
        float mx = -3.0e38f;
#pragma unroll
        for (int i = 0; i < 4; i++) {
            int c = 4 * l + 256 * i;
            ushort4 su = *(const ushort4*)&s[c];
            int4 mv = *(const int4*)&m[c];
            v[4 * i + 0] = mv.x ? bf2f(su.x) : -1e9f;
            v[4 * i + 1] = mv.y ? bf2f(su.y) : -1e9f;
            v[4 * i + 2] = mv.z ? bf2f(su.z) : -1e9f;
            v[4 * i + 3] = mv.w ? bf2f(su.w) : -1e9f;
            mx = fmaxf(mx, fmaxf(fmaxf(v[4 * i], v[4 * i + 1]), fmaxf(v[4 * i + 2], v[4 * i + 3])));
        }
#pragma unroll
        for (int o = 32; o; o >>= 1) mx = fmaxf(mx, __shfl_xor(mx, o, 64));
        float sum = 0.f;
#pragma unroll
        for (int i = 0; i < 16; i++) { v[i] = __expf(v[i] - mx); sum += v[i]; }
#pragma unroll
        for (int o = 32; o; o >>= 1) sum += __shfl_xor(sum, o, 64);
        float inv = 1.0f / sum;
#pragma unroll
        for (int i = 0; i < 4; i++) {
            int c = 4 * l + 256 * i;
            ushort4 st;
            st.x = f2bf(v[4 * i + 0] * inv);
            st.y = f2bf(v[4 * i + 1] * inv);
            st.z = f2bf(v[4 * i + 2] * inv);
            st.w = f2bf(v[4 * i + 3] * inv);
            *(ushort4*)&p[(size_t)row * 1024 + c] = st;
        }
        return;
    }
    bid -= 1024;
    const int z = bid >> 8, t = bid & 255;
    const bf16_t* in = qkv + 2048 + (size_t)z * 1024 * 3072;
    bf16_t* out = vt + (size_t)z * 1024 * 1024;
    const int bx = (t & 15) * 64, by = (t >> 4) * 64;
    const int tid = threadIdx.x;
    const int cj = (tid & 15) * 4, ri = tid >> 4;
#pragma unroll
    for (int k = 0; k < 4; k++) {
        int r = ri + k * 16;
        *(ushort4*)&tls[r][cj] = *(const ushort4*)&in[(size_t)(by + r) * 3072 + bx + cj];
    }
    __syncthreads();
#pragma unroll
    for (int k = 0; k < 4; k++) {
        int i2 = ri + k * 16;
        ushort4 o;
        o.x = __builtin_bit_cast(u16, tls[cj + 0][i2]);
        o.y = __builtin_bit_cast(u16, tls[cj + 1][i2]);
        o.z = __builtin_bit_cast(u16, tls[cj + 2][i2]);
        o.w = __builtin_bit_cast(u16, tls[cj + 3][i2]);
        *(ushort4*)&out[(size_t)(bx + i2) * 1024 + by + cj] = o;
    }
}

// ---------------------------------------------------------------------------
// residual + LayerNorm, bf16 residual stream
// ---------------------------------------------------------------------------
__global__ __launch_bounds__(256)
void ln_kernel(const bf16_t* __restrict__ xin, const bf16_t* __restrict__ add,
               const float* __restrict__ g, const float* __restrict__ beta,
               bf16_t* __restrict__ out)
{
    __shared__ float red[8];
    const int row = blockIdx.x;
    const int t = threadIdx.x;
    const size_t base = (size_t)row * 1024 + t * 4;
    ushort4 xu = *(const ushort4*)&xin[base];
    ushort4 au = *(const ushort4*)&add[base];
    float tv[4];
    tv[0] = bf2f(xu.x) + bf2f(au.x);
    tv[1] = bf2f(xu.y) + bf2f(au.y);
    tv[2] = bf2f(xu.z) + bf2f(au.z);
    tv[3] = bf2f(xu.w) + bf2f(au.w);
    float s = tv[0] + tv[1] + tv[2] + tv[3];
    float s2 = tv[0] * tv[0] + tv[1] * tv[1] + tv[2] * tv[2] + tv[3] * tv[3];
#pragma unroll
    for (int o = 32; o; o >>= 1) { s += __shfl_xor(s, o, 64); s2 += __shfl_xor(s2, o, 64); }
    if ((t & 63) == 0) { red[t >> 6] = s; red[4 + (t >> 6)] = s2; }
    __syncthreads();
    s = red[0] + red[1] + red[2] + red[3];
    s2 = red[4] + red[5] + red[6] + red[7];
    const float mu = s * (1.f / 1024.f);
    const float var = s2 * (1.f / 1024.f) - mu * mu;
    const float rs = rsqrtf(var + 1e-5f);
    float4 gu = *(const float4*)&g[t * 4];
    float4 bu = *(const float4*)&beta[t * 4];
    ushort4 ob;
    ob.x = f2bf((tv[0] - mu) * rs * gu.x + bu.x);
    ob.y = f2bf((tv[1] - mu) * rs * gu.y + bu.y);
    ob.z = f2bf((tv[2] - mu) * rs * gu.z + bu.z);
    ob.w = f2bf((tv[3] - mu) * rs * gu.w + bu.w);
    *(ushort4*)&out[base] = ob;
}

// ---------------------------------------------------------------------------
// residual + 4-plane-sum + bias + LayerNorm (split-K FF2), bf16 residual.
// ---------------------------------------------------------------------------
template <int F32OUT>
__global__ __launch_bounds__(256)
void ln4_kernel(const bf16_t* __restrict__ xin, const bf16_t* __restrict__ p,
                long pstride, const float* __restrict__ fbias,
                const float* __restrict__ g, const float* __restrict__ beta,
                void* __restrict__ outv)
{
    __shared__ float red[8];
    const int row = blockIdx.x;
    const int t = threadIdx.x;
    const size_t base = (size_t)row * 1024 + t * 4;
    ushort4 xu = *(const ushort4*)&xin[base];
    float4 bb = *(const float4*)&fbias[t * 4];
    float tv[4] = {bf2f(xu.x) + bb.x, bf2f(xu.y) + bb.y,
                   bf2f(xu.z) + bb.z, bf2f(xu.w) + bb.w};
#pragma unroll
    for (int z = 0; z < 4; z++) {
        ushort4 au = *(const ushort4*)&p[(size_t)z * pstride + base];
        tv[0] += bf2f(au.x); tv[1] += bf2f(au.y);
        tv[2] += bf2f(au.z); tv[3] += bf2f(au.w);
    }
    float s = tv[0] + tv[1] + tv[2] + tv[3];
    float s2 = tv[0] * tv[0] + tv[1] * tv[1] + tv[2] * tv[2] + tv[3] * tv[3];
#pragma unroll
    for (int o = 32; o; o >>= 1) { s += __shfl_xor(s, o, 64); s2 += __shfl_xor(s2, o, 64); }
    if ((t & 63) == 0) { red[t >> 6] = s; red[4 + (t >> 6)] = s2; }
    __syncthreads();
    s = red[0] + red[1] + red[2] + red[3];
    s2 = red[4] + red[5] + red[6] + red[7];
    const float mu = s * (1.f / 1024.f);
    const float var = s2 * (1.f / 1024.f) - mu * mu;
    const float rs = rsqrtf(var + 1e-5f);
    float4 gu = *(const float4*)&g[t * 4];
    float4 bu = *(const float4*)&beta[t * 4];
    float y0 = (tv[0] - mu) * rs * gu.x + bu.x;
    float y1 = (tv[1] - mu) * rs * gu.y + bu.y;
    float y2 = (tv[2] - mu) * rs * gu.z + bu.z;
    float y3 = (tv[3] - mu) * rs * gu.w + bu.w;
    if (F32OUT) {
        float4 yo = {y0, y1, y2, y3};
        *(float4*)&((float*)outv)[base] = yo;
    } else {
        ushort4 ob = {f2bf(y0), f2bf(y1), f2bf(y2), f2bf(y3)};
        *(ushort4*)&((bf16_t*)outv)[base] = ob;
    }
}

// ---------------------------------------------------------------------------

extern "C" void kernel_launch(void* const* d_in, const int* in_sizes, int n_in,
                              void* d_out, int out_size, void* d_ws, size_t ws_size,
                              hipStream_t stream)
{
    const int*   ids = (const int*)d_in[0];
    const int*   am  = (const int*)d_in[1];
    const float* emb = (const float*)d_in[2];
    const float* Wq  = (const float*)d_in[3];
    const float* Wk  = (const float*)d_in[4];
    const float* Wv  = (const float*)d_in[5];
    const float* bq  = (const float*)d_in[6];
    const float* bk  = (const float*)d_in[7];
    const float* bv  = (const float*)d_in[8];
    const float* g1  = (const float*)d_in[9];
    const float* be1 = (const float*)d_in[10];
    const float* Wf1 = (const float*)d_in[11];
    const float* bf1 = (const float*)d_in[12];
    const float* Wf2 = (const float*)d_in[13];
    const float* bf2_ = (const float*)d_in[14];
    const float* g2  = (const float*)d_in[15];
    const float* be2 = (const float*)d_in[16];

    char* ws = (char*)d_ws;
    bf16_t* xb     = (bf16_t*)(ws + (16LL << 20));      // 8 MB   [16,24)  residual (bf16)
    bf16_t* qkv    = (bf16_t*)(ws + (24LL << 20));      // 24 MB  [24,48)
    bf16_t* vt     = (bf16_t*)(ws + (48LL << 20));      // 8 MB   [48,56)
    bf16_t* fpart  = (bf16_t*)(ws + (24LL << 20));      // 32 MB  [24,56) (aliases qkv/vt)
    bf16_t* scores = (bf16_t*)(ws + (56LL << 20));      // 8 MB   [56,64) (aliases h)
    bf16_t* p      = (bf16_t*)(ws + (72LL << 20));      // 8 MB   [72,80) (aliases h)
    bf16_t* h      = (bf16_t*)(ws + (56LL << 20));      // 32 MB  [56,88)
    bf16_t* attn   = (bf16_t*)(ws + (88LL << 20));      // 8 MB   [88,96)
    bf16_t* wqkvTA = (bf16_t*)(ws + (96LL << 20));      // 36 MB  [96,132)
    bf16_t* wf1TA  = (bf16_t*)(ws + (132LL << 20));     // 48 MB  [132,180)
    bf16_t* wf2TA  = (bf16_t*)(ws + (180LL << 20));     // 48 MB  [180,228)
    float*  qbiasA = (float*)(ws + (228LL << 20));      // 72 KB

    const size_t DD = 1024 * 1024;

    prep_kernel<<<8392, 256, 0, stream>>>(Wq, Wk, Wv, Wf1, Wf2, bq, bk, bv,
                                          ids, emb, wqkvTA, wf1TA, wf2TA, qbiasA, xb);

    for (int l = 0; l < 6; l++) {
        // fused QKV: [4096,1024] x [3072,1024]^T -> qkv [4096,3072]
        gemm8p<0><<<dim3(12, 16, 1), 512, 0, stream>>>(xb, 1024, wqkvTA + (size_t)l * 3 * DD, 1024,
                                                       qkv, 3072, qbiasA + l * 3072, 1024, 0, 0);
        // scores = Q K^T * 1/32  (bf16)
        gemm_db<3><<<dim3(8, 8, 4), 256, 0, stream>>>(qkv, 3072, 1024L * 3072,
                                                      qkv + 1024, 3072, 1024L * 3072,
                                                      scores, 1024, 1024L * 1024,
                                                      nullptr, 1024, 0.03125f);
        // softmax + V^T (merged)
        softvt_kernel<<<2048, 256, 0, stream>>>(scores, am, p, qkv, vt);
        // attn = P V  (via V^T as Bt)
        gemm_db<0><<<dim3(8, 8, 4), 256, 0, stream>>>(p, 1024, 1024L * 1024,
                                                      vt, 1024, 1024L * 1024,
                                                      attn, 1024, 1024L * 1024,
                                                      nullptr, 1024, 0.f);
        ln_kernel<<<4096, 256, 0, stream>>>(xb, attn, g1 + l * 1024, be1 + l * 1024, xb);
        // FF1 with relu -> h [4096,4096]
        gemm8p<1><<<dim3(16, 16, 1), 512, 0, stream>>>(xb, 1024, wf1TA + (size_t)l * 4 * DD, 1024,
                                                       h, 4096, bf1 + l * 4096, 1024, 0, 0);
        // FF2 split-K=4 -> fpart
        gemm8p<0><<<dim3(4, 16, 4), 512, 0, stream>>>(h, 4096, wf2TA + (size_t)l * 4 * DD, 4096,
                                                      fpart, 1024, nullptr, 1024,
                                                      1024, 4096L * 1024);
        if (l == 5)
            ln4_kernel<1><<<4096, 256, 0, stream>>>(xb, fpart, 4096L * 1024, bf2_ + l * 1024,
                                                    g2 + l * 1024, be2 + l * 1024, d_out);
        else
            ln4_kernel<0><<<4096, 256, 0, stream>>>(xb, fpart, 4096L * 1024, bf2_ + l * 1024,
                                                    g2 + l * 1024, be2 + l * 1024, xb);
    }
    (void)in_sizes; (void)n_in; (void)out_size; (void)ws_size;
}

// Round 15
// 1173.897 us; speedup vs baseline: 1.0596x; 1.0596x over previous
//
#include <hip/hip_runtime.h>

typedef __bf16 bf16_t;
typedef __bf16 bf16x8 __attribute__((ext_vector_type(8)));
typedef float f32x4 __attribute__((ext_vector_type(4)));
typedef float f32x16 __attribute__((ext_vector_type(16)));
typedef unsigned short u16;

#define DEV static __device__ __forceinline__

DEV float bf2f(u16 u) { __bf16 h = __builtin_bit_cast(__bf16, u); return (float)h; }
DEV u16 f2bf(float f) { __bf16 h = (__bf16)f; return __builtin_bit_cast(u16, h); }

// async global->LDS, 16B per lane; lds base must be wave-uniform.
DEV void gll16(bf16_t* lds, const bf16_t* g) {
    __builtin_amdgcn_global_load_lds(
        (const __attribute__((address_space(1))) void*)g,
        (__attribute__((address_space(3))) void*)lds, 16, 0, 0);
}

#define WAITV(N) asm volatile("s_waitcnt vmcnt(" #N ")" ::: "memory")

// ---------------------------------------------------------------------------
// 256x256-tile GEMM, 8 waves (2M x 4N), BK=64, double-buffered 128KiB LDS,
// round-11 schedule (pairs 1,2 in region 1; pair 3 in region 2; WAITV(2)),
// 32x32x16 MFMA. Confirmed local optimum over 5 schedule variants.
// EPI: 0 = bf16 out (+f32 bias if non-null), 1 = bf16 out + bias + relu
// ---------------------------------------------------------------------------
template <int EPI>
__global__ __launch_bounds__(512, 1)
void gemm8p(const bf16_t* __restrict__ A, int lda,
            const bf16_t* __restrict__ Bt, int ldb,
            bf16_t* __restrict__ C, int ldc,
            const float* __restrict__ bias, int K,
            long kadv, long cadv)
{
    __shared__ bf16_t Asm[2 * 2 * 8192];   // [buf][half][128*64]
    __shared__ bf16_t Bsm[2 * 2 * 8192];
    const int tid = threadIdx.x, w = tid >> 6, l = tid & 63;
    const int z = blockIdx.z;
    A  += (size_t)z * kadv;
    Bt += (size_t)z * kadv;
    C  += (size_t)z * cadv;

    const int gx = gridDim.x;
    int lin = blockIdx.y * gx + blockIdx.x;
    const int nlin = gx * gridDim.y;
    lin = (lin & 7) * (nlin >> 3) + (lin >> 3);
    const size_t row0 = (size_t)(lin / gx) * 256;
    const size_t col0 = (size_t)(lin % gx) * 256;

    const int wr = w >> 2, wc = w & 3;
    const int bh = wc >> 1;
    const int browoff = (wc & 1) * 64;
    const int r32 = l & 31, hk = l >> 5, sw = l & 7;

    const int srow = w * 8 + (l >> 3);
    const int sslot8 = ((l & 7) ^ ((l >> 3) & 7)) * 8;
    const bf16_t* AgH0 = A  + (row0 + srow) * (size_t)lda + sslot8;
    const bf16_t* BgH0 = Bt + (col0 + srow) * (size_t)ldb + sslot8;
    const size_t a128 = (size_t)128 * lda, b128 = (size_t)128 * ldb;
    const size_t a64  = (size_t)64 * lda,  b64  = (size_t)64 * ldb;
    const int wlds = w * 512;

#define STAGE_PAIR(buf, tt, p)                                                 \
    do {                                                                       \
        const int koff = (tt) * 64;                                            \
        if ((p) == 0) {                                                        \
            gll16(Asm + ((buf)*2+0)*8192 + wlds,        AgH0 + koff);          \
            gll16(Asm + ((buf)*2+0)*8192 + 4096 + wlds, AgH0 + koff + a64);    \
        } else if ((p) == 1) {                                                 \
            gll16(Asm + ((buf)*2+1)*8192 + wlds,        AgH0 + a128 + koff);   \
            gll16(Asm + ((buf)*2+1)*8192 + 4096 + wlds, AgH0 + a128 + koff + a64); \
        } else if ((p) == 2) {                                                 \
            gll16(Bsm + ((buf)*2+0)*8192 + wlds,        BgH0 + koff);          \
            gll16(Bsm + ((buf)*2+0)*8192 + 4096 + wlds, BgH0 + koff + b64);    \
        } else {                                                               \
            gll16(Bsm + ((buf)*2+1)*8192 + wlds,        BgH0 + b128 + koff);   \
            gll16(Bsm + ((buf)*2+1)*8192 + 4096 + wlds, BgH0 + b128 + koff + b64); \
        }                                                                      \
    } while (0)

    f32x16 acc[4][2] = {};
    const int NT = K >> 6;

    STAGE_PAIR(0, 0, 0); STAGE_PAIR(0, 0, 1); STAGE_PAIR(0, 0, 2); STAGE_PAIR(0, 0, 3);
    if (NT > 1) { STAGE_PAIR(1, 1, 0); WAITV(2); } else { WAITV(0); }
    __builtin_amdgcn_sched_barrier(0);
    __builtin_amdgcn_s_barrier();

    for (int t = 0; t < NT; ++t) {
        const int cur = t & 1, nxt = cur ^ 1;
        const bool hasN1 = (t + 1 < NT), hasN2 = (t + 2 < NT);
        const bf16_t* Ab = Asm + (cur * 2 + wr) * 8192;
        const bf16_t* Bb = Bsm + (cur * 2 + bh) * 8192;

        // region 1: read B(all) + A(mi0-1); stage t+1 pairs 1,2; 16 MFMA
        bf16x8 bR[2][4], aR[2][4];
#pragma unroll
        for (int ni = 0; ni < 2; ni++)
#pragma unroll
            for (int ks = 0; ks < 4; ks++)
                bR[ni][ks] = *(const bf16x8*)&Bb[(browoff + ni * 32 + r32) * 64 + ((ks * 2 + hk) ^ sw) * 8];
#pragma unroll
        for (int mi = 0; mi < 2; mi++)
#pragma unroll
            for (int ks = 0; ks < 4; ks++)
                aR[mi][ks] = *(const bf16x8*)&Ab[(mi * 32 + r32) * 64 + ((ks * 2 + hk) ^ sw) * 8];
        if (hasN1) { STAGE_PAIR(nxt, t + 1, 1); STAGE_PAIR(nxt, t + 1, 2); }
        __builtin_amdgcn_s_setprio(1);
#pragma unroll
        for (int mi = 0; mi < 2; mi++)
#pragma unroll
            for (int ni = 0; ni < 2; ni++)
#pragma unroll
                for (int ks = 0; ks < 4; ks++)
                    acc[mi][ni] = __builtin_amdgcn_mfma_f32_32x32x16_bf16(aR[mi][ks], bR[ni][ks], acc[mi][ni], 0, 0, 0);
        __builtin_amdgcn_s_setprio(0);

        // region 2: read A(mi2-3); stage t+1 pair 3; 16 MFMA
        bf16x8 a2[2][4];
#pragma unroll
        for (int mi = 0; mi < 2; mi++)
#pragma unroll
            for (int ks = 0; ks < 4; ks++)
                a2[mi][ks] = *(const bf16x8*)&Ab[((2 + mi) * 32 + r32) * 64 + ((ks * 2 + hk) ^ sw) * 8];
        if (hasN1) STAGE_PAIR(nxt, t + 1, 3);
        __builtin_amdgcn_s_setprio(1);
#pragma unroll
        for (int mi = 0; mi < 2; mi++)
#pragma unroll
            for (int ni = 0; ni < 2; ni++)
#pragma unroll
                for (int ks = 0; ks < 4; ks++)
                    acc[2 + mi][ni] = __builtin_amdgcn_mfma_f32_32x32x16_bf16(a2[mi][ks], bR[ni][ks], acc[2 + mi][ni], 0, 0, 0);
        __builtin_amdgcn_s_setprio(0);

        __builtin_amdgcn_s_barrier();      // all reads of cur drained
        if (hasN2) STAGE_PAIR(cur, t + 2, 0);
        if (hasN1) {
            if (hasN2) { WAITV(2); } else { WAITV(0); }
            __builtin_amdgcn_sched_barrier(0);
        }
        __builtin_amdgcn_s_barrier();      // t+1 buffer published
    }
#undef STAGE_PAIR

#pragma unroll
    for (int ni = 0; ni < 2; ni++) {
        size_t c = col0 + wc * 64 + ni * 32 + r32;
        float bv = bias ? bias[c] : 0.f;
#pragma unroll
        for (int mi = 0; mi < 4; mi++) {
            size_t rb = row0 + wr * 128 + mi * 32 + hk * 4;
#pragma unroll
            for (int reg = 0; reg < 16; reg++) {
                size_t r = rb + (reg & 3) + 8 * (reg >> 2);
                float v = acc[mi][ni][reg] + bv;
                if (EPI == 1) v = fmaxf(v, 0.f);
                C[r * ldc + c] = (bf16_t)v;
            }
        }
    }
}

// ---------------------------------------------------------------------------
// 128x128-tile GEMM, 4 waves, BK=64, dbuf LDS, 32x32x16 MFMA (round-11).
// EPI: 0 bf16+bias, 1 +relu, 2 f32*scale, 3 bf16*scale
// ---------------------------------------------------------------------------
template <int EPI>
__global__ __launch_bounds__(256)
void gemm_db(const bf16_t* __restrict__ A, int lda, long sA,
             const bf16_t* __restrict__ Bt, int ldb, long sB,
             void* __restrict__ Cv, int ldc, long sC,
             const float* __restrict__ bias, int K, float scale)
{
    __shared__ bf16_t Asm[2][128 * 64];
    __shared__ bf16_t Bsm[2][128 * 64];
    const int tid = threadIdx.x, w = tid >> 6, l = tid & 63;
    const int bz = blockIdx.z;

    const int gx = gridDim.x;
    int lin = blockIdx.y * gx + blockIdx.x;
    const int nlin = gx * gridDim.y;
    lin = (lin & 7) * (nlin >> 3) + (lin >> 3);
    const size_t row0 = (size_t)(lin / gx) * 128;
    const size_t col0 = (size_t)(lin % gx) * 128;

    A  += (size_t)bz * sA;
    Bt += (size_t)bz * sB;

    const int lr = l >> 3;
    const int sl = (l & 7) ^ lr;
    const bf16_t* Ag = A  + (row0 + (size_t)(w * 32) + lr) * lda + sl * 8;
    const bf16_t* Bg = Bt + (col0 + (size_t)(w * 32) + lr) * ldb + sl * 8;
    const int wlds = (w * 32) * 64;

#define STA(buf, tt)                                                           \
    do { const int ko = (tt) * 64;                                             \
        _Pragma("unroll")                                                      \
        for (int c = 0; c < 4; c++)                                            \
            gll16(&Asm[buf][wlds + c * 8 * 64], Ag + (size_t)(c * 8) * lda + ko); \
    } while (0)
#define STB(buf, tt)                                                           \
    do { const int ko = (tt) * 64;                                             \
        _Pragma("unroll")                                                      \
        for (int c = 0; c < 4; c++)                                            \
            gll16(&Bsm[buf][wlds + c * 8 * 64], Bg + (size_t)(c * 8) * ldb + ko); \
    } while (0)

    const int wm = (w >> 1) * 64, wn = (w & 1) * 64;
    const int r32 = l & 31, hk = l >> 5, sw = l & 7;
    f32x16 acc[2][2] = {};
    const int NT = K >> 6;

    STA(0, 0); STB(0, 0);
    if (NT > 1) { STA(1, 1); WAITV(4); } else { WAITV(0); }
    __builtin_amdgcn_sched_barrier(0);
    __builtin_amdgcn_s_barrier();

    for (int t = 0; t < NT; ++t) {
        const int cur = t & 1, nxt = cur ^ 1;
        const bool hasN1 = (t + 1 < NT), hasN2 = (t + 2 < NT);

        bf16x8 a0[2][2], b0[2][2];
#pragma unroll
        for (int i = 0; i < 2; i++)
#pragma unroll
            for (int ks = 0; ks < 2; ks++) {
                a0[i][ks] = *(const bf16x8*)&Asm[cur][(wm + i * 32 + r32) * 64 + ((ks * 2 + hk) ^ sw) * 8];
                b0[i][ks] = *(const bf16x8*)&Bsm[cur][(wn + i * 32 + r32) * 64 + ((ks * 2 + hk) ^ sw) * 8];
            }
        if (hasN1) STB(nxt, t + 1);
        __builtin_amdgcn_s_setprio(1);
#pragma unroll
        for (int mi = 0; mi < 2; mi++)
#pragma unroll
            for (int ni = 0; ni < 2; ni++)
#pragma unroll
                for (int ks = 0; ks < 2; ks++)
                    acc[mi][ni] = __builtin_amdgcn_mfma_f32_32x32x16_bf16(a0[mi][ks], b0[ni][ks], acc[mi][ni], 0, 0, 0);
        __builtin_amdgcn_s_setprio(0);

        bf16x8 a1[2][2], b1[2][2];
#pragma unroll
        for (int i = 0; i < 2; i++)
#pragma unroll
            for (int ks = 0; ks < 2; ks++) {
                a1[i][ks] = *(const bf16x8*)&Asm[cur][(wm + i * 32 + r32) * 64 + (((2 + ks) * 2 + hk) ^ sw) * 8];
                b1[i][ks] = *(const bf16x8*)&Bsm[cur][(wn + i * 32 + r32) * 64 + (((2 + ks) * 2 + hk) ^ sw) * 8];
            }
        __builtin_amdgcn_s_setprio(1);
#pragma unroll
        for (int mi = 0; mi < 2; mi++)
#pragma unroll
            for (int ni = 0; ni < 2; ni++)
#pragma unroll
                for (int ks = 0; ks < 2; ks++)
                    acc[mi][ni] = __builtin_amdgcn_mfma_f32_32x32x16_bf16(a1[mi][ks], b1[ni][ks], acc[mi][ni], 0, 0, 0);
        __builtin_amdgcn_s_setprio(0);

        __builtin_amdgcn_s_barrier();
        if (hasN2) STA(cur, t + 2);
        if (hasN1) {
            if (hasN2) { WAITV(4); } else { WAITV(0); }
            __builtin_amdgcn_sched_barrier(0);
        }
        __builtin_amdgcn_s_barrier();
    }
#undef STA
#undef STB

#pragma unroll
    for (int ni = 0; ni < 2; ni++) {
        size_t c = col0 + wn + ni * 32 + r32;
        float bv = (EPI == 0 || EPI == 1) ? (bias ? bias[c] : 0.f) : 0.f;
#pragma unroll
        for (int mi = 0; mi < 2; mi++) {
            size_t rb = row0 + wm + mi * 32 + hk * 4;
#pragma unroll
            for (int reg = 0; reg < 16; reg++) {
                size_t r = rb + (reg & 3) + 8 * (reg >> 2);
                float v = acc[mi][ni][reg];
                if (EPI == 2) {
                    ((float*)Cv + (size_t)bz * sC)[r * ldc + c] = v * scale;
                } else if (EPI == 3) {
                    ((bf16_t*)Cv + (size_t)bz * sC)[r * ldc + c] = (bf16_t)(v * scale);
                } else {
                    v += bv;
                    if (EPI == 1) v = fmaxf(v, 0.f);
                    ((bf16_t*)Cv + (size_t)bz * sC)[r * ldc + c] = (bf16_t)v;
                }
            }
        }
    }
}

// ---------------------------------------------------------------------------
// one-shot preprocessing (round-13 version).
// ---------------------------------------------------------------------------
__global__ __launch_bounds__(256)
void prep_kernel(const float* __restrict__ Wq, const float* __restrict__ Wk,
                 const float* __restrict__ Wv, const float* __restrict__ Wf1,
                 const float* __restrict__ Wf2,
                 const float* __restrict__ bq, const float* __restrict__ bk,
                 const float* __restrict__ bv,
                 const int* __restrict__ ids, const float* __restrict__ emb,
                 bf16_t* __restrict__ wqkvTA, bf16_t* __restrict__ wf1TA,
                 bf16_t* __restrict__ wf2TA, float* __restrict__ qbiasA,
                 bf16_t* __restrict__ xb)
{
    __shared__ bf16_t tls[4][64 * 64];   // 32 KB
    const size_t DD = 1024 * 1024;
    int id = blockIdx.x;
    if (id < 4224) {
        const float* src; bf16_t* dst; int ldin, ldout, bx, by;
        if (id < 1152) {
            int layer = id / 192, r = id % 192, which = r >> 6, t = r & 63;
            src = (which == 0 ? Wq : which == 1 ? Wk : Wv) + (size_t)layer * DD;
            dst = wqkvTA + (size_t)layer * 3 * DD + (size_t)which * DD;
            ldin = 1024; ldout = 1024; bx = (t & 15) * 64; by = (t >> 4) * 256;
        } else if (id < 2688) {
            int i = id - 1152, layer = i >> 8, t = i & 255;
            src = Wf1 + (size_t)layer * 4 * DD; dst = wf1TA + (size_t)layer * 4 * DD;
            ldin = 4096; ldout = 1024; bx = (t & 63) * 64; by = (t >> 6) * 256;
        } else {
            int i = id - 2688, layer = i >> 8, t = i & 255;
            src = Wf2 + (size_t)layer * 4 * DD; dst = wf2TA + (size_t)layer * 4 * DD;
            ldin = 1024; ldout = 4096; bx = (t & 15) * 64; by = (t >> 4) * 256;
        }
        const int tid = threadIdx.x;
        const int cg = tid & 15, ri = tid >> 4;
#pragma unroll
        for (int sub = 0; sub < 4; sub++) {
#pragma unroll
            for (int k = 0; k < 4; k++) {
                int r = ri + k * 16;
                float4 v = *(const float4*)&src[(size_t)(by + sub * 64 + r) * ldin + bx + cg * 4];
                ushort4 o = {f2bf(v.x), f2bf(v.y), f2bf(v.z), f2bf(v.w)};
                int g = (cg ^ ((r >> 2) & 15) ^ sub) & 15;
                *(ushort4*)&tls[sub][r * 64 + g * 4] = o;
            }
        }
        __syncthreads();
        const int c = tid & 31, sub = c >> 3, j = c & 7;
#pragma unroll
        for (int p = 0; p < 8; p++) {
            int i = p * 8 + (tid >> 5);
            u16 vals[8];
#pragma unroll
            for (int m = 0; m < 8; m++) {
                int rr = j * 8 + m;
                int gg = ((i >> 2) ^ (rr >> 2) ^ sub) & 15;
                vals[m] = __builtin_bit_cast(u16, tls[sub][rr * 64 + gg * 4 + (i & 3)]);
            }
            uint4 ov;
            ov.x = (unsigned)vals[0] | ((unsigned)vals[1] << 16);
            ov.y = (unsigned)vals[2] | ((unsigned)vals[3] << 16);
            ov.z = (unsigned)vals[4] | ((unsigned)vals[5] << 16);
            ov.w = (unsigned)vals[6] | ((unsigned)vals[7] << 16);
            *(uint4*)&dst[(size_t)(bx + i) * ldout + by + c * 8] = ov;
        }
        return;
    }
    id -= 4224;
    if (id < 72) {
        int i = id * 256 + threadIdx.x;
        int lyr = i / 3072, j = i - lyr * 3072;
        qbiasA[i] = (j < 1024) ? bq[lyr * 1024 + j]
                  : (j < 2048) ? bk[lyr * 1024 + j - 1024]
                               : bv[lyr * 1024 + j - 2048];
        return;
    }
    id -= 72;
    const int row = id;
    const int s = row & 1023;
    const int eid = ids[row];
    const float* er = emb + (size_t)eid * 1024;
    bf16_t* br = xb + (size_t)row * 1024;
#pragma unroll
    for (int k = 0; k < 2; k++) {
        int i = threadIdx.x + 256 * k;
        int d = 2 * i;
        float dv = expf((float)d * -0.008994473019508f);
        float ph = (float)s * dv;
        float sv, cv;
        sincosf(ph, &sv, &cv);
        float2 ev = *(const float2*)&er[d];
        ushort2 bo = {f2bf(ev.x + sv), f2bf(ev.y + cv)};
        *(ushort2*)&br[d] = bo;
    }
}

// ---------------------------------------------------------------------------
// merged masked-softmax over bf16 scores (blocks 0..1023) + V^T transpose
// (blocks 1024..2047).
// ---------------------------------------------------------------------------
__global__ __launch_bounds__(256)
void softvt_kernel(const bf16_t* __restrict__ sc, const int* __restrict__ amask,
                   bf16_t* __restrict__ p, const bf16_t* __restrict__ qkv,
                   bf16_t* __restrict__ vt)
{
    __shared__ bf16_t tls[64][72];
    int bid = blockIdx.x;
    if (bid < 1024) {
        const int row = bid * 4 + (threadIdx.x >> 6);
        const int l = threadIdx.x & 63;
        const int b = row >> 10;
        const bf16_t* s = sc + (size_t)row * 1024;
        const int* m = amask + (size_t)b * 1024;
        float v[16];
        float mx = -3.0e38f;
#pragma unroll
        for (int i = 0; i < 4; i++) {
            int c = 4 * l + 256 * i;
            ushort4 su = *(const ushort4*)&s[c];
            int4 mv = *(const int4*)&m[c];
            v[4 * i + 0] = mv.x ? bf2f(su.x) : -1e9f;
            v[4 * i + 1] = mv.y ? bf2f(su.y) : -1e9f;
            v[4 * i + 2] = mv.z ? bf2f(su.z) : -1e9f;
            v[4 * i + 3] = mv.w ? bf2f(su.w) : -1e9f;
            mx = fmaxf(mx, fmaxf(fmaxf(v[4 * i], v[4 * i + 1]), fmaxf(v[4 * i + 2], v[4 * i + 3])));
        }
#pragma unroll
        for (int o = 32; o; o >>= 1) mx = fmaxf(mx, __shfl_xor(mx, o, 64));
        float sum = 0.f;
#pragma unroll
        for (int i = 0; i < 16; i++) { v[i] = __expf(v[i] - mx); sum += v[i]; }
#pragma unroll
        for (int o = 32; o; o >>= 1) sum += __shfl_xor(sum, o, 64);
        float inv = 1.0f / sum;
#pragma unroll
        for (int i = 0; i < 4; i++) {
            int c = 4 * l + 256 * i;
            ushort4 st;
            st.x = f2bf(v[4 * i + 0] * inv);
            st.y = f2bf(v[4 * i + 1] * inv);
            st.z = f2bf(v[4 * i + 2] * inv);
            st.w = f2bf(v[4 * i + 3] * inv);
            *(ushort4*)&p[(size_t)row * 1024 + c] = st;
        }
        return;
    }
    bid -= 1024;
    const int z = bid >> 8, t = bid & 255;
    const bf16_t* in = qkv + 2048 + (size_t)z * 1024 * 3072;
    bf16_t* out = vt + (size_t)z * 1024 * 1024;
    const int bx = (t & 15) * 64, by = (t >> 4) * 64;
    const int tid = threadIdx.x;
    const int cj = (tid & 15) * 4, ri = tid >> 4;
#pragma unroll
    for (int k = 0; k < 4; k++) {
        int r = ri + k * 16;
        *(ushort4*)&tls[r][cj] = *(const ushort4*)&in[(size_t)(by + r) * 3072 + bx + cj];
    }
    __syncthreads();
#pragma unroll
    for (int k = 0; k < 4; k++) {
        int i2 = ri + k * 16;
        ushort4 o;
        o.x = __builtin_bit_cast(u16, tls[cj + 0][i2]);
        o.y = __builtin_bit_cast(u16, tls[cj + 1][i2]);
        o.z = __builtin_bit_cast(u16, tls[cj + 2][i2]);
        o.w = __builtin_bit_cast(u16, tls[cj + 3][i2]);
        *(ushort4*)&out[(size_t)(bx + i2) * 1024 + by + cj] = o;
    }
}

// ---------------------------------------------------------------------------
// residual + LayerNorm, bf16 residual stream
// ---------------------------------------------------------------------------
__global__ __launch_bounds__(256)
void ln_kernel(const bf16_t* __restrict__ xin, const bf16_t* __restrict__ add,
               const float* __restrict__ g, const float* __restrict__ beta,
               bf16_t* __restrict__ out)
{
    __shared__ float red[8];
    const int row = blockIdx.x;
    const int t = threadIdx.x;
    const size_t base = (size_t)row * 1024 + t * 4;
    ushort4 xu = *(const ushort4*)&xin[base];
    ushort4 au = *(const ushort4*)&add[base];
    float tv[4];
    tv[0] = bf2f(xu.x) + bf2f(au.x);
    tv[1] = bf2f(xu.y) + bf2f(au.y);
    tv[2] = bf2f(xu.z) + bf2f(au.z);
    tv[3] = bf2f(xu.w) + bf2f(au.w);
    float s = tv[0] + tv[1] + tv[2] + tv[3];
    float s2 = tv[0] * tv[0] + tv[1] * tv[1] + tv[2] * tv[2] + tv[3] * tv[3];
#pragma unroll
    for (int o = 32; o; o >>= 1) { s += __shfl_xor(s, o, 64); s2 += __shfl_xor(s2, o, 64); }
    if ((t & 63) == 0) { red[t >> 6] = s; red[4 + (t >> 6)] = s2; }
    __syncthreads();
    s = red[0] + red[1] + red[2] + red[3];
    s2 = red[4] + red[5] + red[6] + red[7];
    const float mu = s * (1.f / 1024.f);
    const float var = s2 * (1.f / 1024.f) - mu * mu;
    const float rs = rsqrtf(var + 1e-5f);
    float4 gu = *(const float4*)&g[t * 4];
    float4 bu = *(const float4*)&beta[t * 4];
    ushort4 ob;
    ob.x = f2bf((tv[0] - mu) * rs * gu.x + bu.x);
    ob.y = f2bf((tv[1] - mu) * rs * gu.y + bu.y);
    ob.z = f2bf((tv[2] - mu) * rs * gu.z + bu.z);
    ob.w = f2bf((tv[3] - mu) * rs * gu.w + bu.w);
    *(ushort4*)&out[base] = ob;
}

// ---------------------------------------------------------------------------
// residual + 4-plane-sum + bias + LayerNorm (split-K FF2), bf16 residual.
// ---------------------------------------------------------------------------
template <int F32OUT>
__global__ __launch_bounds__(256)
void ln4_kernel(const bf16_t* __restrict__ xin, const bf16_t* __restrict__ p,
                long pstride, const float* __restrict__ fbias,
                const float* __restrict__ g, const float* __restrict__ beta,
                void* __restrict__ outv)
{
    __shared__ float red[8];
    const int row = blockIdx.x;
    const int t = threadIdx.x;
    const size_t base = (size_t)row * 1024 + t * 4;
    ushort4 xu = *(const ushort4*)&xin[base];
    float4 bb = *(const float4*)&fbias[t * 4];
    float tv[4] = {bf2f(xu.x) + bb.x, bf2f(xu.y) + bb.y,
                   bf2f(xu.z) + bb.z, bf2f(xu.w) + bb.w};
#pragma unroll
    for (int z = 0; z < 4; z++) {
        ushort4 au = *(const ushort4*)&p[(size_t)z * pstride + base];
        tv[0] += bf2f(au.x); tv[1] += bf2f(au.y);
        tv[2] += bf2f(au.z); tv[3] += bf2f(au.w);
    }
    float s = tv[0] + tv[1] + tv[2] + tv[3];
    float s2 = tv[0] * tv[0] + tv[1] * tv[1] + tv[2] * tv[2] + tv[3] * tv[3];
#pragma unroll
    for (int o = 32; o; o >>= 1) { s += __shfl_xor(s, o, 64); s2 += __shfl_xor(s2, o, 64); }
    if ((t & 63) == 0) { red[t >> 6] = s; red[4 + (t >> 6)] = s2; }
    __syncthreads();
    s = red[0] + red[1] + red[2] + red[3];
    s2 = red[4] + red[5] + red[6] + red[7];
    const float mu = s * (1.f / 1024.f);
    const float var = s2 * (1.f / 1024.f) - mu * mu;
    const float rs = rsqrtf(var + 1e-5f);
    float4 gu = *(const float4*)&g[t * 4];
    float4 bu = *(const float4*)&beta[t * 4];
    float y0 = (tv[0] - mu) * rs * gu.x + bu.x;
    float y1 = (tv[1] - mu) * rs * gu.y + bu.y;
    float y2 = (tv[2] - mu) * rs * gu.z + bu.z;
    float y3 = (tv[3] - mu) * rs * gu.w + bu.w;
    if (F32OUT) {
        float4 yo = {y0, y1, y2, y3};
        *(float4*)&((float*)outv)[base] = yo;
    } else {
        ushort4 ob = {f2bf(y0), f2bf(y1), f2bf(y2), f2bf(y3)};
        *(ushort4*)&((bf16_t*)outv)[base] = ob;
    }
}

// ---------------------------------------------------------------------------

extern "C" void kernel_launch(void* const* d_in, const int* in_sizes, int n_in,
                              void* d_out, int out_size, void* d_ws, size_t ws_size,
                              hipStream_t stream)
{
    const int*   ids = (const int*)d_in[0];
    const int*   am  = (const int*)d_in[1];
    const float* emb = (const float*)d_in[2];
    const float* Wq  = (const float*)d_in[3];
    const float* Wk  = (const float*)d_in[4];
    const float* Wv  = (const float*)d_in[5];
    const float* bq  = (const float*)d_in[6];
    const float* bk  = (const float*)d_in[7];
    const float* bv  = (const float*)d_in[8];
    const float* g1  = (const float*)d_in[9];
    const float* be1 = (const float*)d_in[10];
    const float* Wf1 = (const float*)d_in[11];
    const float* bf1 = (const float*)d_in[12];
    const float* Wf2 = (const float*)d_in[13];
    const float* bf2_ = (const float*)d_in[14];
    const float* g2  = (const float*)d_in[15];
    const float* be2 = (const float*)d_in[16];

    char* ws = (char*)d_ws;
    bf16_t* xb     = (bf16_t*)(ws + (16LL << 20));      // 8 MB   [16,24)  residual (bf16)
    bf16_t* qkv    = (bf16_t*)(ws + (24LL << 20));      // 24 MB  [24,48)
    bf16_t* vt     = (bf16_t*)(ws + (48LL << 20));      // 8 MB   [48,56)
    bf16_t* fpart  = (bf16_t*)(ws + (24LL << 20));      // 32 MB  [24,56) (aliases qkv/vt)
    bf16_t* scores = (bf16_t*)(ws + (56LL << 20));      // 8 MB   [56,64) (aliases h)
    bf16_t* p      = (bf16_t*)(ws + (72LL << 20));      // 8 MB   [72,80) (aliases h)
    bf16_t* h      = (bf16_t*)(ws + (56LL << 20));      // 32 MB  [56,88)
    bf16_t* attn   = (bf16_t*)(ws + (88LL << 20));      // 8 MB   [88,96)
    bf16_t* wqkvTA = (bf16_t*)(ws + (96LL << 20));      // 36 MB  [96,132)
    bf16_t* wf1TA  = (bf16_t*)(ws + (132LL << 20));     // 48 MB  [132,180)
    bf16_t* wf2TA  = (bf16_t*)(ws + (180LL << 20));     // 48 MB  [180,228)
    float*  qbiasA = (float*)(ws + (228LL << 20));      // 72 KB

    const size_t DD = 1024 * 1024;

    prep_kernel<<<8392, 256, 0, stream>>>(Wq, Wk, Wv, Wf1, Wf2, bq, bk, bv,
                                          ids, emb, wqkvTA, wf1TA, wf2TA, qbiasA, xb);

    for (int l = 0; l < 6; l++) {
        // fused QKV: [4096,1024] x [3072,1024]^T -> qkv [4096,3072]
        gemm8p<0><<<dim3(12, 16, 1), 512, 0, stream>>>(xb, 1024, wqkvTA + (size_t)l * 3 * DD, 1024,
                                                       qkv, 3072, qbiasA + l * 3072, 1024, 0, 0);
        // scores = Q K^T * 1/32  (bf16)
        gemm_db<3><<<dim3(8, 8, 4), 256, 0, stream>>>(qkv, 3072, 1024L * 3072,
                                                      qkv + 1024, 3072, 1024L * 3072,
                                                      scores, 1024, 1024L * 1024,
                                                      nullptr, 1024, 0.03125f);
        // softmax + V^T (merged)
        softvt_kernel<<<2048, 256, 0, stream>>>(scores, am, p, qkv, vt);
        // attn = P V  (via V^T as Bt)
        gemm_db<0><<<dim3(8, 8, 4), 256, 0, stream>>>(p, 1024, 1024L * 1024,
                                                      vt, 1024, 1024L * 1024,
                                                      attn, 1024, 1024L * 1024,
                                                      nullptr, 1024, 0.f);
        ln_kernel<<<4096, 256, 0, stream>>>(xb, attn, g1 + l * 1024, be1 + l * 1024, xb);
        // FF1 with relu -> h [4096,4096]
        gemm8p<1><<<dim3(16, 16, 1), 512, 0, stream>>>(xb, 1024, wf1TA + (size_t)l * 4 * DD, 1024,
                                                       h, 4096, bf1 + l * 4096, 1024, 0, 0);
        // FF2 split-K=4 -> fpart
        gemm8p<0><<<dim3(4, 16, 4), 512, 0, stream>>>(h, 4096, wf2TA + (size_t)l * 4 * DD, 4096,
                                                      fpart, 1024, nullptr, 1024,
                                                      1024, 4096L * 1024);
        if (l == 5)
            ln4_kernel<1><<<4096, 256, 0, stream>>>(xb, fpart, 4096L * 1024, bf2_ + l * 1024,
                                                    g2 + l * 1024, be2 + l * 1024, d_out);
        else
            ln4_kernel<0><<<4096, 256, 0, stream>>>(xb, fpart, 4096L * 1024, bf2_ + l * 1024,
                                                    g2 + l * 1024, be2 + l * 1024, xb);
    }
    (void)in_sizes; (void)n_in; (void)out_size; (void)ws_size;
}

// Round 16
// 1144.385 us; speedup vs baseline: 1.0869x; 1.0258x over previous
//
#include <hip/hip_runtime.h>

typedef __bf16 bf16_t;
typedef __bf16 bf16x8 __attribute__((ext_vector_type(8)));
typedef float f32x4 __attribute__((ext_vector_type(4)));
typedef float f32x16 __attribute__((ext_vector_type(16)));
typedef unsigned short u16;

#define DEV static __device__ __forceinline__

DEV float bf2f(u16 u) { __bf16 h = __builtin_bit_cast(__bf16, u); return (float)h; }
DEV u16 f2bf(float f) { __bf16 h = (__bf16)f; return __builtin_bit_cast(u16, h); }

// async global->LDS, 16B per lane; lds base must be wave-uniform.
DEV void gll16(bf16_t* lds, const bf16_t* g) {
    __builtin_amdgcn_global_load_lds(
        (const __attribute__((address_space(1))) void*)g,
        (__attribute__((address_space(3))) void*)lds, 16, 0, 0);
}

#define WAITV(N) asm volatile("s_waitcnt vmcnt(" #N ")" ::: "memory")

// ---------------------------------------------------------------------------
// 256x256-tile GEMM, 8 waves (2M x 4N), BK=64, double-buffered 128KiB LDS,
// round-11 schedule (pairs 1,2 in region 1; pair 3 in region 2; WAITV(2)),
// 32x32x16 MFMA. Confirmed local optimum over 5 schedule variants.
// EPI: 0 = bf16 out (+f32 bias if non-null), 1 = bf16 out + bias + relu
// ---------------------------------------------------------------------------
template <int EPI>
__global__ __launch_bounds__(512, 1)
void gemm8p(const bf16_t* __restrict__ A, int lda,
            const bf16_t* __restrict__ Bt, int ldb,
            bf16_t* __restrict__ C, int ldc,
            const float* __restrict__ bias, int K,
            long kadv, long cadv)
{
    __shared__ bf16_t Asm[2 * 2 * 8192];   // [buf][half][128*64]
    __shared__ bf16_t Bsm[2 * 2 * 8192];
    const int tid = threadIdx.x, w = tid >> 6, l = tid & 63;
    const int z = blockIdx.z;
    A  += (size_t)z * kadv;
    Bt += (size_t)z * kadv;
    C  += (size_t)z * cadv;

    const int gx = gridDim.x;
    int lin = blockIdx.y * gx + blockIdx.x;
    const int nlin = gx * gridDim.y;
    lin = (lin & 7) * (nlin >> 3) + (lin >> 3);
    const size_t row0 = (size_t)(lin / gx) * 256;
    const size_t col0 = (size_t)(lin % gx) * 256;

    const int wr = w >> 2, wc = w & 3;
    const int bh = wc >> 1;
    const int browoff = (wc & 1) * 64;
    const int r32 = l & 31, hk = l >> 5, sw = l & 7;

    const int srow = w * 8 + (l >> 3);
    const int sslot8 = ((l & 7) ^ ((l >> 3) & 7)) * 8;
    const bf16_t* AgH0 = A  + (row0 + srow) * (size_t)lda + sslot8;
    const bf16_t* BgH0 = Bt + (col0 + srow) * (size_t)ldb + sslot8;
    const size_t a128 = (size_t)128 * lda, b128 = (size_t)128 * ldb;
    const size_t a64  = (size_t)64 * lda,  b64  = (size_t)64 * ldb;
    const int wlds = w * 512;

#define STAGE_PAIR(buf, tt, p)                                                 \
    do {                                                                       \
        const int koff = (tt) * 64;                                            \
        if ((p) == 0) {                                                        \
            gll16(Asm + ((buf)*2+0)*8192 + wlds,        AgH0 + koff);          \
            gll16(Asm + ((buf)*2+0)*8192 + 4096 + wlds, AgH0 + koff + a64);    \
        } else if ((p) == 1) {                                                 \
            gll16(Asm + ((buf)*2+1)*8192 + wlds,        AgH0 + a128 + koff);   \
            gll16(Asm + ((buf)*2+1)*8192 + 4096 + wlds, AgH0 + a128 + koff + a64); \
        } else if ((p) == 2) {                                                 \
            gll16(Bsm + ((buf)*2+0)*8192 + wlds,        BgH0 + koff);          \
            gll16(Bsm + ((buf)*2+0)*8192 + 4096 + wlds, BgH0 + koff + b64);    \
        } else {                                                               \
            gll16(Bsm + ((buf)*2+1)*8192 + wlds,        BgH0 + b128 + koff);   \
            gll16(Bsm + ((buf)*2+1)*8192 + 4096 + wlds, BgH0 + b128 + koff + b64); \
        }                                                                      \
    } while (0)

    f32x16 acc[4][2] = {};
    const int NT = K >> 6;

    STAGE_PAIR(0, 0, 0); STAGE_PAIR(0, 0, 1); STAGE_PAIR(0, 0, 2); STAGE_PAIR(0, 0, 3);
    if (NT > 1) { STAGE_PAIR(1, 1, 0); WAITV(2); } else { WAITV(0); }
    __builtin_amdgcn_sched_barrier(0);
    __builtin_amdgcn_s_barrier();

    for (int t = 0; t < NT; ++t) {
        const int cur = t & 1, nxt = cur ^ 1;
        const bool hasN1 = (t + 1 < NT), hasN2 = (t + 2 < NT);
        const bf16_t* Ab = Asm + (cur * 2 + wr) * 8192;
        const bf16_t* Bb = Bsm + (cur * 2 + bh) * 8192;

        // region 1: read B(all) + A(mi0-1); stage t+1 pairs 1,2; 16 MFMA
        bf16x8 bR[2][4], aR[2][4];
#pragma unroll
        for (int ni = 0; ni < 2; ni++)
#pragma unroll
            for (int ks = 0; ks < 4; ks++)
                bR[ni][ks] = *(const bf16x8*)&Bb[(browoff + ni * 32 + r32) * 64 + ((ks * 2 + hk) ^ sw) * 8];
#pragma unroll
        for (int mi = 0; mi < 2; mi++)
#pragma unroll
            for (int ks = 0; ks < 4; ks++)
                aR[mi][ks] = *(const bf16x8*)&Ab[(mi * 32 + r32) * 64 + ((ks * 2 + hk) ^ sw) * 8];
        if (hasN1) { STAGE_PAIR(nxt, t + 1, 1); STAGE_PAIR(nxt, t + 1, 2); }
        __builtin_amdgcn_s_setprio(1);
#pragma unroll
        for (int mi = 0; mi < 2; mi++)
#pragma unroll
            for (int ni = 0; ni < 2; ni++)
#pragma unroll
                for (int ks = 0; ks < 4; ks++)
                    acc[mi][ni] = __builtin_amdgcn_mfma_f32_32x32x16_bf16(aR[mi][ks], bR[ni][ks], acc[mi][ni], 0, 0, 0);
        __builtin_amdgcn_s_setprio(0);

        // region 2: read A(mi2-3); stage t+1 pair 3; 16 MFMA
        bf16x8 a2[2][4];
#pragma unroll
        for (int mi = 0; mi < 2; mi++)
#pragma unroll
            for (int ks = 0; ks < 4; ks++)
                a2[mi][ks] = *(const bf16x8*)&Ab[((2 + mi) * 32 + r32) * 64 + ((ks * 2 + hk) ^ sw) * 8];
        if (hasN1) STAGE_PAIR(nxt, t + 1, 3);
        __builtin_amdgcn_s_setprio(1);
#pragma unroll
        for (int mi = 0; mi < 2; mi++)
#pragma unroll
            for (int ni = 0; ni < 2; ni++)
#pragma unroll
                for (int ks = 0; ks < 4; ks++)
                    acc[2 + mi][ni] = __builtin_amdgcn_mfma_f32_32x32x16_bf16(a2[mi][ks], bR[ni][ks], acc[2 + mi][ni], 0, 0, 0);
        __builtin_amdgcn_s_setprio(0);

        __builtin_amdgcn_s_barrier();      // all reads of cur drained
        if (hasN2) STAGE_PAIR(cur, t + 2, 0);
        if (hasN1) {
            if (hasN2) { WAITV(2); } else { WAITV(0); }
            __builtin_amdgcn_sched_barrier(0);
        }
        __builtin_amdgcn_s_barrier();      // t+1 buffer published
    }
#undef STAGE_PAIR

#pragma unroll
    for (int ni = 0; ni < 2; ni++) {
        size_t c = col0 + wc * 64 + ni * 32 + r32;
        float bv = bias ? bias[c] : 0.f;
#pragma unroll
        for (int mi = 0; mi < 4; mi++) {
            size_t rb = row0 + wr * 128 + mi * 32 + hk * 4;
#pragma unroll
            for (int reg = 0; reg < 16; reg++) {
                size_t r = rb + (reg & 3) + 8 * (reg >> 2);
                float v = acc[mi][ni][reg] + bv;
                if (EPI == 1) v = fmaxf(v, 0.f);
                C[r * ldc + c] = (bf16_t)v;
            }
        }
    }
}

// ---------------------------------------------------------------------------
// 128x128-tile GEMM, now 512 threads / 8 waves (2M x 4N, wave tile 64x32),
// BK=64, dbuf LDS (64 KiB), r11 schedule, 32x32x16 MFMA. 8 waves/CU = 2/SIMD
// restores cross-wave MFMA||ds_read overlap at grid=1 block/CU.
// EPI: 0 bf16+bias, 1 +relu, 2 f32*scale, 3 bf16*scale
// ---------------------------------------------------------------------------
template <int EPI>
__global__ __launch_bounds__(512, 1)
void gemm_db(const bf16_t* __restrict__ A, int lda, long sA,
             const bf16_t* __restrict__ Bt, int ldb, long sB,
             void* __restrict__ Cv, int ldc, long sC,
             const float* __restrict__ bias, int K, float scale)
{
    __shared__ bf16_t Asm[2][128 * 64];
    __shared__ bf16_t Bsm[2][128 * 64];
    const int tid = threadIdx.x, w = tid >> 6, l = tid & 63;
    const int bz = blockIdx.z;

    const int gx = gridDim.x;
    int lin = blockIdx.y * gx + blockIdx.x;
    const int nlin = gx * gridDim.y;
    lin = (lin & 7) * (nlin >> 3) + (lin >> 3);
    const size_t row0 = (size_t)(lin / gx) * 128;
    const size_t col0 = (size_t)(lin % gx) * 128;

    A  += (size_t)bz * sA;
    Bt += (size_t)bz * sB;

    // staging: 512 threads cover 64 rows x 8 slots per issue; 2 issues/tile
    const int srow = w * 8 + (l >> 3);
    const int sslot8 = ((l & 7) ^ ((l >> 3) & 7)) * 8;
    const bf16_t* Ag = A  + (row0 + srow) * (size_t)lda + sslot8;
    const bf16_t* Bg = Bt + (col0 + srow) * (size_t)ldb + sslot8;
    const size_t a64 = (size_t)64 * lda, b64 = (size_t)64 * ldb;
    const int wlds = w * 512;

#define STA(buf, tt)                                                           \
    do { const int ko = (tt) * 64;                                             \
        gll16(&Asm[buf][wlds],        Ag + ko);                                \
        gll16(&Asm[buf][4096 + wlds], Ag + ko + a64);                          \
    } while (0)
#define STB(buf, tt)                                                           \
    do { const int ko = (tt) * 64;                                             \
        gll16(&Bsm[buf][wlds],        Bg + ko);                                \
        gll16(&Bsm[buf][4096 + wlds], Bg + ko + b64);                          \
    } while (0)

    const int wm = (w >> 2) * 64, wn = (w & 3) * 32;   // 2M x 4N waves
    const int r32 = l & 31, hk = l >> 5, sw = l & 7;
    f32x16 acc[2];           // [mi], single ni
    acc[0] = (f32x16)(0.f); acc[1] = (f32x16)(0.f);
    const int NT = K >> 6;

    STA(0, 0); STB(0, 0);
    if (NT > 1) { STA(1, 1); WAITV(2); } else { WAITV(0); }
    __builtin_amdgcn_sched_barrier(0);
    __builtin_amdgcn_s_barrier();

    for (int t = 0; t < NT; ++t) {
        const int cur = t & 1, nxt = cur ^ 1;
        const bool hasN1 = (t + 1 < NT), hasN2 = (t + 2 < NT);

        // region 1: read B(all 4ks) + A(mi0); stage B(t+1); 4 MFMA
        bf16x8 bF[4], aF[4];
#pragma unroll
        for (int ks = 0; ks < 4; ks++)
            bF[ks] = *(const bf16x8*)&Bsm[cur][(wn + r32) * 64 + ((ks * 2 + hk) ^ sw) * 8];
#pragma unroll
        for (int ks = 0; ks < 4; ks++)
            aF[ks] = *(const bf16x8*)&Asm[cur][(wm + r32) * 64 + ((ks * 2 + hk) ^ sw) * 8];
        if (hasN1) STB(nxt, t + 1);
        __builtin_amdgcn_s_setprio(1);
#pragma unroll
        for (int ks = 0; ks < 4; ks++)
            acc[0] = __builtin_amdgcn_mfma_f32_32x32x16_bf16(aF[ks], bF[ks], acc[0], 0, 0, 0);
        __builtin_amdgcn_s_setprio(0);

        // region 2: read A(mi1); 4 MFMA
        bf16x8 a2[4];
#pragma unroll
        for (int ks = 0; ks < 4; ks++)
            a2[ks] = *(const bf16x8*)&Asm[cur][(wm + 32 + r32) * 64 + ((ks * 2 + hk) ^ sw) * 8];
        __builtin_amdgcn_s_setprio(1);
#pragma unroll
        for (int ks = 0; ks < 4; ks++)
            acc[1] = __builtin_amdgcn_mfma_f32_32x32x16_bf16(a2[ks], bF[ks], acc[1], 0, 0, 0);
        __builtin_amdgcn_s_setprio(0);

        __builtin_amdgcn_s_barrier();      // reads of cur drained
        if (hasN2) STA(cur, t + 2);
        if (hasN1) {
            if (hasN2) { WAITV(2); } else { WAITV(0); }
            __builtin_amdgcn_sched_barrier(0);
        }
        __builtin_amdgcn_s_barrier();
    }
#undef STA
#undef STB

    {
        size_t c = col0 + wn + r32;
        float bv = (EPI == 0 || EPI == 1) ? (bias ? bias[c] : 0.f) : 0.f;
#pragma unroll
        for (int mi = 0; mi < 2; mi++) {
            size_t rb = row0 + wm + mi * 32 + hk * 4;
#pragma unroll
            for (int reg = 0; reg < 16; reg++) {
                size_t r = rb + (reg & 3) + 8 * (reg >> 2);
                float v = acc[mi][reg];
                if (EPI == 2) {
                    ((float*)Cv + (size_t)bz * sC)[r * ldc + c] = v * scale;
                } else if (EPI == 3) {
                    ((bf16_t*)Cv + (size_t)bz * sC)[r * ldc + c] = (bf16_t)(v * scale);
                } else {
                    v += bv;
                    if (EPI == 1) v = fmaxf(v, 0.f);
                    ((bf16_t*)Cv + (size_t)bz * sC)[r * ldc + c] = (bf16_t)v;
                }
            }
        }
    }
}

// ---------------------------------------------------------------------------
// one-shot preprocessing (round-13 version).
// ---------------------------------------------------------------------------
__global__ __launch_bounds__(256)
void prep_kernel(const float* __restrict__ Wq, const float* __restrict__ Wk,
                 const float* __restrict__ Wv, const float* __restrict__ Wf1,
                 const float* __restrict__ Wf2,
                 const float* __restrict__ bq, const float* __restrict__ bk,
                 const float* __restrict__ bv,
                 const int* __restrict__ ids, const float* __restrict__ emb,
                 bf16_t* __restrict__ wqkvTA, bf16_t* __restrict__ wf1TA,
                 bf16_t* __restrict__ wf2TA, float* __restrict__ qbiasA,
                 bf16_t* __restrict__ xb)
{
    __shared__ bf16_t tls[4][64 * 64];   // 32 KB
    const size_t DD = 1024 * 1024;
    int id = blockIdx.x;
    if (id < 4224) {
        const float* src; bf16_t* dst; int ldin, ldout, bx, by;
        if (id < 1152) {
            int layer = id / 192, r = id % 192, which = r >> 6, t = r & 63;
            src = (which == 0 ? Wq : which == 1 ? Wk : Wv) + (size_t)layer * DD;
            dst = wqkvTA + (size_t)layer * 3 * DD + (size_t)which * DD;
            ldin = 1024; ldout = 1024; bx = (t & 15) * 64; by = (t >> 4) * 256;
        } else if (id < 2688) {
            int i = id - 1152, layer = i >> 8, t = i & 255;
            src = Wf1 + (size_t)layer * 4 * DD; dst = wf1TA + (size_t)layer * 4 * DD;
            ldin = 4096; ldout = 1024; bx = (t & 63) * 64; by = (t >> 6) * 256;
        } else {
            int i = id - 2688, layer = i >> 8, t = i & 255;
            src = Wf2 + (size_t)layer * 4 * DD; dst = wf2TA + (size_t)layer * 4 * DD;
            ldin = 1024; ldout = 4096; bx = (t & 15) * 64; by = (t >> 4) * 256;
        }
        const int tid = threadIdx.x;
        const int cg = tid & 15, ri = tid >> 4;
#pragma unroll
        for (int sub = 0; sub < 4; sub++) {
#pragma unroll
            for (int k = 0; k < 4; k++) {
                int r = ri + k * 16;
                float4 v = *(const float4*)&src[(size_t)(by + sub * 64 + r) * ldin + bx + cg * 4];
                ushort4 o = {f2bf(v.x), f2bf(v.y), f2bf(v.z), f2bf(v.w)};
                int g = (cg ^ ((r >> 2) & 15) ^ sub) & 15;
                *(ushort4*)&tls[sub][r * 64 + g * 4] = o;
            }
        }
        __syncthreads();
        const int c = tid & 31, sub = c >> 3, j = c & 7;
#pragma unroll
        for (int p = 0; p < 8; p++) {
            int i = p * 8 + (tid >> 5);
            u16 vals[8];
#pragma unroll
            for (int m = 0; m < 8; m++) {
                int rr = j * 8 + m;
                int gg = ((i >> 2) ^ (rr >> 2) ^ sub) & 15;
                vals[m] = __builtin_bit_cast(u16, tls[sub][rr * 64 + gg * 4 + (i & 3)]);
            }
            uint4 ov;
            ov.x = (unsigned)vals[0] | ((unsigned)vals[1] << 16);
            ov.y = (unsigned)vals[2] | ((unsigned)vals[3] << 16);
            ov.z = (unsigned)vals[4] | ((unsigned)vals[5] << 16);
            ov.w = (unsigned)vals[6] | ((unsigned)vals[7] << 16);
            *(uint4*)&dst[(size_t)(bx + i) * ldout + by + c * 8] = ov;
        }
        return;
    }
    id -= 4224;
    if (id < 72) {
        int i = id * 256 + threadIdx.x;
        int lyr = i / 3072, j = i - lyr * 3072;
        qbiasA[i] = (j < 1024) ? bq[lyr * 1024 + j]
                  : (j < 2048) ? bk[lyr * 1024 + j - 1024]
                               : bv[lyr * 1024 + j - 2048];
        return;
    }
    id -= 72;
    const int row = id;
    const int s = row & 1023;
    const int eid = ids[row];
    const float* er = emb + (size_t)eid * 1024;
    bf16_t* br = xb + (size_t)row * 1024;
#pragma unroll
    for (int k = 0; k < 2; k++) {
        int i = threadIdx.x + 256 * k;
        int d = 2 * i;
        float dv = expf((float)d * -0.008994473019508f);
        float ph = (float)s * dv;
        float sv, cv;
        sincosf(ph, &sv, &cv);
        float2 ev = *(const float2*)&er[d];
        ushort2 bo = {f2bf(ev.x + sv), f2bf(ev.y + cv)};
        *(ushort2*)&br[d] = bo;
    }
}

// ---------------------------------------------------------------------------
// merged masked-softmax over bf16 scores (blocks 0..1023) + V^T transpose
// (blocks 1024..2047).
// ---------------------------------------------------------------------------
__global__ __launch_bounds__(256)
void softvt_kernel(const bf16_t* __restrict__ sc, const int* __restrict__ amask,
                   bf16_t* __restrict__ p, const bf16_t* __restrict__ qkv,
                   bf16_t* __restrict__ vt)
{
    __shared__ bf16_t tls[64][72];
    int bid = blockIdx.x;
    if (bid < 1024) {
        const int row = bid * 4 + (threadIdx.x >> 6);
        const int l = threadIdx.x & 63;
        const int b = row >> 10;
        const bf16_t* s = sc + (size_t)row * 1024;
        const int* m = amask + (size_t)b * 1024;
        float v[16];
        float mx = -3.0e38f;
#pragma unroll
        for (int i = 0; i < 4; i++) {
            int c = 4 * l + 256 * i;
            ushort4 su = *(const ushort4*)&s[c];
            int4 mv = *(const int4*)&m[c];
            v[4 * i + 0] = mv.x ? bf2f(su.x) : -1e9f;
            v[4 * i + 1] = mv.y ? bf2f(su.y) : -1e9f;
            v[4 * i + 2] = mv.z ? bf2f(su.z) : -1e9f;
            v[4 * i + 3] = mv.w ? bf2f(su.w) : -1e9f;
            mx = fmaxf(mx, fmaxf(fmaxf(v[4 * i], v[4 * i + 1]), fmaxf(v[4 * i + 2], v[4 * i + 3])));
        }
#pragma unroll
        for (int o = 32; o; o >>= 1) mx = fmaxf(mx, __shfl_xor(mx, o, 64));
        float sum = 0.f;
#pragma unroll
        for (int i = 0; i < 16; i++) { v[i] = __expf(v[i] - mx); sum += v[i]; }
#pragma unroll
        for (int o = 32; o; o >>= 1) sum += __shfl_xor(sum, o, 64);
        float inv = 1.0f / sum;
#pragma unroll
        for (int i = 0; i < 4; i++) {
            int c = 4 * l + 256 * i;
            ushort4 st;
            st.x = f2bf(v[4 * i + 0] * inv);
            st.y = f2bf(v[4 * i + 1] * inv);
            st.z = f2bf(v[4 * i + 2] * inv);
            st.w = f2bf(v[4 * i + 3] * inv);
            *(ushort4*)&p[(size_t)row * 1024 + c] = st;
        }
        return;
    }
    bid -= 1024;
    const int z = bid >> 8, t = bid & 255;
    const bf16_t* in = qkv + 2048 + (size_t)z * 1024 * 3072;
    bf16_t* out = vt + (size_t)z * 1024 * 1024;
    const int bx = (t & 15) * 64, by = (t >> 4) * 64;
    const int tid = threadIdx.x;
    const int cj = (tid & 15) * 4, ri = tid >> 4;
#pragma unroll
    for (int k = 0; k < 4; k++) {
        int r = ri + k * 16;
        *(ushort4*)&tls[r][cj] = *(const ushort4*)&in[(size_t)(by + r) * 3072 + bx + cj];
    }
    __syncthreads();
#pragma unroll
    for (int k = 0; k < 4; k++) {
        int i2 = ri + k * 16;
        ushort4 o;
        o.x = __builtin_bit_cast(u16, tls[cj + 0][i2]);
        o.y = __builtin_bit_cast(u16, tls[cj + 1][i2]);
        o.z = __builtin_bit_cast(u16, tls[cj + 2][i2]);
        o.w = __builtin_bit_cast(u16, tls[cj + 3][i2]);
        *(ushort4*)&out[(size_t)(bx + i2) * 1024 + by + cj] = o;
    }
}

// ---------------------------------------------------------------------------
// residual + LayerNorm, bf16 residual stream
// ---------------------------------------------------------------------------
__global__ __launch_bounds__(256)
void ln_kernel(const bf16_t* __restrict__ xin, const bf16_t* __restrict__ add,
               const float* __restrict__ g, const float* __restrict__ beta,
               bf16_t* __restrict__ out)
{
    __shared__ float red[8];
    const int row = blockIdx.x;
    const int t = threadIdx.x;
    const size_t base = (size_t)row * 1024 + t * 4;
    ushort4 xu = *(const ushort4*)&xin[base];
    ushort4 au = *(const ushort4*)&add[base];
    float tv[4];
    tv[0] = bf2f(xu.x) + bf2f(au.x);
    tv[1] = bf2f(xu.y) + bf2f(au.y);
    tv[2] = bf2f(xu.z) + bf2f(au.z);
    tv[3] = bf2f(xu.w) + bf2f(au.w);
    float s = tv[0] + tv[1] + tv[2] + tv[3];
    float s2 = tv[0] * tv[0] + tv[1] * tv[1] + tv[2] * tv[2] + tv[3] * tv[3];
#pragma unroll
    for (int o = 32; o; o >>= 1) { s += __shfl_xor(s, o, 64); s2 += __shfl_xor(s2, o, 64); }
    if ((t & 63) == 0) { red[t >> 6] = s; red[4 + (t >> 6)] = s2; }
    __syncthreads();
    s = red[0] + red[1] + red[2] + red[3];
    s2 = red[4] + red[5] + red[6] + red[7];
    const float mu = s * (1.f / 1024.f);
    const float var = s2 * (1.f / 1024.f) - mu * mu;
    const float rs = rsqrtf(var + 1e-5f);
    float4 gu = *(const float4*)&g[t * 4];
    float4 bu = *(const float4*)&beta[t * 4];
    ushort4 ob;
    ob.x = f2bf((tv[0] - mu) * rs * gu.x + bu.x);
    ob.y = f2bf((tv[1] - mu) * rs * gu.y + bu.y);
    ob.z = f2bf((tv[2] - mu) * rs * gu.z + bu.z);
    ob.w = f2bf((tv[3] - mu) * rs * gu.w + bu.w);
    *(ushort4*)&out[base] = ob;
}

// ---------------------------------------------------------------------------
// residual + 4-plane-sum + bias + LayerNorm (split-K FF2), bf16 residual.
// ---------------------------------------------------------------------------
template <int F32OUT>
__global__ __launch_bounds__(256)
void ln4_kernel(const bf16_t* __restrict__ xin, const bf16_t* __restrict__ p,
                long pstride, const float* __restrict__ fbias,
                const float* __restrict__ g, const float* __restrict__ beta,
                void* __restrict__ outv)
{
    __shared__ float red[8];
    const int row = blockIdx.x;
    const int t = threadIdx.x;
    const size_t base = (size_t)row * 1024 + t * 4;
    ushort4 xu = *(const ushort4*)&xin[base];
    float4 bb = *(const float4*)&fbias[t * 4];
    float tv[4] = {bf2f(xu.x) + bb.x, bf2f(xu.y) + bb.y,
                   bf2f(xu.z) + bb.z, bf2f(xu.w) + bb.w};
#pragma unroll
    for (int z = 0; z < 4; z++) {
        ushort4 au = *(const ushort4*)&p[(size_t)z * pstride + base];
        tv[0] += bf2f(au.x); tv[1] += bf2f(au.y);
        tv[2] += bf2f(au.z); tv[3] += bf2f(au.w);
    }
    float s = tv[0] + tv[1] + tv[2] + tv[3];
    float s2 = tv[0] * tv[0] + tv[1] * tv[1] + tv[2] * tv[2] + tv[3] * tv[3];
#pragma unroll
    for (int o = 32; o; o >>= 1) { s += __shfl_xor(s, o, 64); s2 += __shfl_xor(s2, o, 64); }
    if ((t & 63) == 0) { red[t >> 6] = s; red[4 + (t >> 6)] = s2; }
    __syncthreads();
    s = red[0] + red[1] + red[2] + red[3];
    s2 = red[4] + red[5] + red[6] + red[7];
    const float mu = s * (1.f / 1024.f);
    const float var = s2 * (1.f / 1024.f) - mu * mu;
    const float rs = rsqrtf(var + 1e-5f);
    float4 gu = *(const float4*)&g[t * 4];
    float4 bu = *(const float4*)&beta[t * 4];
    float y0 = (tv[0] - mu) * rs * gu.x + bu.x;
    float y1 = (tv[1] - mu) * rs * gu.y + bu.y;
    float y2 = (tv[2] - mu) * rs * gu.z + bu.z;
    float y3 = (tv[3] - mu) * rs * gu.w + bu.w;
    if (F32OUT) {
        float4 yo = {y0, y1, y2, y3};
        *(float4*)&((float*)outv)[base] = yo;
    } else {
        ushort4 ob = {f2bf(y0), f2bf(y1), f2bf(y2), f2bf(y3)};
        *(ushort4*)&((bf16_t*)outv)[base] = ob;
    }
}

// ---------------------------------------------------------------------------

extern "C" void kernel_launch(void* const* d_in, const int* in_sizes, int n_in,
                              void* d_out, int out_size, void* d_ws, size_t ws_size,
                              hipStream_t stream)
{
    const int*   ids = (const int*)d_in[0];
    const int*   am  = (const int*)d_in[1];
    const float* emb = (const float*)d_in[2];
    const float* Wq  = (const float*)d_in[3];
    const float* Wk  = (const float*)d_in[4];
    const float* Wv  = (const float*)d_in[5];
    const float* bq  = (const float*)d_in[6];
    const float* bk  = (const float*)d_in[7];
    const float* bv  = (const float*)d_in[8];
    const float* g1  = (const float*)d_in[9];
    const float* be1 = (const float*)d_in[10];
    const float* Wf1 = (const float*)d_in[11];
    const float* bf1 = (const float*)d_in[12];
    const float* Wf2 = (const float*)d_in[13];
    const float* bf2_ = (const float*)d_in[14];
    const float* g2  = (const float*)d_in[15];
    const float* be2 = (const float*)d_in[16];

    char* ws = (char*)d_ws;
    bf16_t* xb     = (bf16_t*)(ws + (16LL << 20));      // 8 MB   [16,24)  residual (bf16)
    bf16_t* qkv    = (bf16_t*)(ws + (24LL << 20));      // 24 MB  [24,48)
    bf16_t* vt     = (bf16_t*)(ws + (48LL << 20));      // 8 MB   [48,56)
    bf16_t* fpart  = (bf16_t*)(ws + (24LL << 20));      // 32 MB  [24,56) (aliases qkv/vt)
    bf16_t* scores = (bf16_t*)(ws + (56LL << 20));      // 8 MB   [56,64) (aliases h)
    bf16_t* p      = (bf16_t*)(ws + (72LL << 20));      // 8 MB   [72,80) (aliases h)
    bf16_t* h      = (bf16_t*)(ws + (56LL << 20));      // 32 MB  [56,88)
    bf16_t* attn   = (bf16_t*)(ws + (88LL << 20));      // 8 MB   [88,96)
    bf16_t* wqkvTA = (bf16_t*)(ws + (96LL << 20));      // 36 MB  [96,132)
    bf16_t* wf1TA  = (bf16_t*)(ws + (132LL << 20));     // 48 MB  [132,180)
    bf16_t* wf2TA  = (bf16_t*)(ws + (180LL << 20));     // 48 MB  [180,228)
    float*  qbiasA = (float*)(ws + (228LL << 20));      // 72 KB

    const size_t DD = 1024 * 1024;

    prep_kernel<<<8392, 256, 0, stream>>>(Wq, Wk, Wv, Wf1, Wf2, bq, bk, bv,
                                          ids, emb, wqkvTA, wf1TA, wf2TA, qbiasA, xb);

    for (int l = 0; l < 6; l++) {
        // fused QKV: [4096,1024] x [3072,1024]^T -> qkv [4096,3072]
        gemm8p<0><<<dim3(12, 16, 1), 512, 0, stream>>>(xb, 1024, wqkvTA + (size_t)l * 3 * DD, 1024,
                                                       qkv, 3072, qbiasA + l * 3072, 1024, 0, 0);
        // scores = Q K^T * 1/32  (bf16)
        gemm_db<3><<<dim3(8, 8, 4), 512, 0, stream>>>(qkv, 3072, 1024L * 3072,
                                                      qkv + 1024, 3072, 1024L * 3072,
                                                      scores, 1024, 1024L * 1024,
                                                      nullptr, 1024, 0.03125f);
        // softmax + V^T (merged)
        softvt_kernel<<<2048, 256, 0, stream>>>(scores, am, p, qkv, vt);
        // attn = P V  (via V^T as Bt)
        gemm_db<0><<<dim3(8, 8, 4), 512, 0, stream>>>(p, 1024, 1024L * 1024,
                                                      vt, 1024, 1024L * 1024,
                                                      attn, 1024, 1024L * 1024,
                                                      nullptr, 1024, 0.f);
        ln_kernel<<<4096, 256, 0, stream>>>(xb, attn, g1 + l * 1024, be1 + l * 1024, xb);
        // FF1 with relu -> h [4096,4096]
        gemm8p<1><<<dim3(16, 16, 1), 512, 0, stream>>>(xb, 1024, wf1TA + (size_t)l * 4 * DD, 1024,
                                                       h, 4096, bf1 + l * 4096, 1024, 0, 0);
        // FF2 split-K=4 -> fpart
        gemm8p<0><<<dim3(4, 16, 4), 512, 0, stream>>>(h, 4096, wf2TA + (size_t)l * 4 * DD, 4096,
                                                      fpart, 1024, nullptr, 1024,
                                                      1024, 4096L * 1024);
        if (l == 5)
            ln4_kernel<1><<<4096, 256, 0, stream>>>(xb, fpart, 4096L * 1024, bf2_ + l * 1024,
                                                    g2 + l * 1024, be2 + l * 1024, d_out);
        else
            ln4_kernel<0><<<4096, 256, 0, stream>>>(xb, fpart, 4096L * 1024, bf2_ + l * 1024,
                                                    g2 + l * 1024, be2 + l * 1024, xb);
    }
    (void)in_sizes; (void)n_in; (void)out_size; (void)ws_size;
}